// Round 2
// baseline (608.844 us; speedup 1.0000x reference)
//
#include <hip/hip_runtime.h>
#include <hip/hip_bf16.h>

#define D 128
#define K 8
#define BGRAPH 64

// ---------------------------------------------------------------------------
// Stage 1a: in-degree histogram over dst
// ---------------------------------------------------------------------------
__global__ __launch_bounds__(256) void hist_kernel(
    const int* __restrict__ dst, int* __restrict__ deg, int E)
{
    const int i = blockIdx.x * 256 + threadIdx.x;
    if (i < E) atomicAdd(&deg[dst[i]], 1);
}

// ---------------------------------------------------------------------------
// Stage 1b: exclusive prefix sum over deg[N] -> offs[N+1]; cursor = copy.
// Single block of 1024 threads, chunked + Hillis-Steele over partials.
// ---------------------------------------------------------------------------
__global__ __launch_bounds__(1024) void scan_kernel(
    const int* __restrict__ deg, int* __restrict__ offs,
    int* __restrict__ cursor, int N)
{
    const int T = 1024;
    const int t = threadIdx.x;
    const int chunk = (N + T - 1) / T;
    const int s = t * chunk;
    const int e = min(s + chunk, N);

    int sum = 0;
    for (int i = s; i < e; ++i) sum += deg[i];

    __shared__ int part[1024];
    part[t] = sum;
    __syncthreads();
    for (int off = 1; off < T; off <<= 1) {
        const int v = (t >= off) ? part[t - off] : 0;
        __syncthreads();
        part[t] += v;
        __syncthreads();
    }
    int base = (t == 0) ? 0 : part[t - 1];
    for (int i = s; i < e; ++i) {
        offs[i] = base;
        cursor[i] = base;
        base += deg[i];
    }
    if (t == T - 1) offs[N] = base;
}

// ---------------------------------------------------------------------------
// Stage 1c: scatter edge ids into dst-grouped order
// ---------------------------------------------------------------------------
__global__ __launch_bounds__(256) void scatter_kernel(
    const int* __restrict__ dst, int* __restrict__ cursor,
    int* __restrict__ perm, int E)
{
    const int i = blockIdx.x * 256 + threadIdx.x;
    if (i < E) {
        const int p = atomicAdd(&cursor[dst[i]], 1);
        perm[p] = i;
    }
}

// ---------------------------------------------------------------------------
// Stage 1d: gather-reduce. One wave per dst node; register accumulate;
// one float2 store per lane per node. No atomics, no agg memset.
//   agg[n] = sum over incoming edges e of relu(x[src[e]] + ea[e] @ We + be)
// ---------------------------------------------------------------------------
__global__ __launch_bounds__(256) void gine_reduce_kernel(
    const float* __restrict__ x, const int* __restrict__ src,
    const float* __restrict__ ea, const int* __restrict__ offs,
    const int* __restrict__ perm, const float* __restrict__ We,
    const float* __restrict__ be, float* __restrict__ agg, int N)
{
    __shared__ float sWe[16 * D];
    __shared__ float sbe[D];
    for (int i = threadIdx.x; i < 16 * D; i += 256) sWe[i] = We[i];
    if (threadIdx.x < D) sbe[threadIdx.x] = be[threadIdx.x];
    __syncthreads();

    const int wave = threadIdx.x >> 6;
    const int lane = threadIdx.x & 63;
    const int node = blockIdx.x * 4 + wave;
    if (node >= N) return;
    const int d = lane * 2;
    const float2 bb = *(const float2*)(sbe + d);

    float2 acc = make_float2(0.f, 0.f);
    const int e0 = offs[node];
    const int e1 = offs[node + 1];
    for (int e = e0; e < e1; ++e) {
        const int eid = perm[e];                     // wave-uniform
        const int sn  = src[eid];                    // wave-uniform
        const float4* a4 = (const float4*)(ea + (size_t)eid * 16);
        const float4 a0 = a4[0], a1 = a4[1], a2 = a4[2], a3 = a4[3];
        const float2 xv = *(const float2*)(x + (size_t)sn * D + d);
        float m0 = bb.x + xv.x;
        float m1 = bb.y + xv.y;
        const float av[16] = {a0.x, a0.y, a0.z, a0.w, a1.x, a1.y, a1.z, a1.w,
                              a2.x, a2.y, a2.z, a2.w, a3.x, a3.y, a3.z, a3.w};
        #pragma unroll
        for (int j = 0; j < 16; ++j) {
            const float2 w = *(const float2*)(sWe + j * D + d);
            m0 += av[j] * w.x;
            m1 += av[j] * w.y;
        }
        acc.x += m0 > 0.f ? m0 : 0.f;
        acc.y += m1 > 0.f ? m1 : 0.f;
    }
    *(float2*)(agg + (size_t)node * D + d) = acc;
}

// ---------------------------------------------------------------------------
// Stage 2: fused 2-layer MLP on h = (1+eps)*x + agg
//   x_res = relu(h @ W1 + b1) @ W2 + b2
// ---------------------------------------------------------------------------
#define MLP_RB 32
__global__ __launch_bounds__(256) void mlp_kernel(
    const float* __restrict__ x, const float* __restrict__ agg,
    const float* __restrict__ epsp,
    const float* __restrict__ W1, const float* __restrict__ b1,
    const float* __restrict__ W2, const float* __restrict__ b2,
    float* __restrict__ xres, int N)
{
    __shared__ float sh[MLP_RB * D];
    __shared__ float st[MLP_RB * D];
    const int row0 = blockIdx.x * MLP_RB;
    const float ep = 1.0f + epsp[0];

    for (int i = threadIdx.x; i < MLP_RB * D / 4; i += 256) {
        const int idx = i * 4;
        const int r = idx >> 7;
        const int c = idx & (D - 1);
        const int row = row0 + r;
        float4 hv;
        if (row < N) {
            const float4 xv = *(const float4*)(x   + (size_t)row * D + c);
            const float4 av = *(const float4*)(agg + (size_t)row * D + c);
            hv = make_float4(ep * xv.x + av.x, ep * xv.y + av.y,
                             ep * xv.z + av.z, ep * xv.w + av.w);
        } else {
            hv = make_float4(0.f, 0.f, 0.f, 0.f);
        }
        *(float4*)(sh + idx) = hv;
    }
    __syncthreads();

    const int d  = threadIdx.x & (D - 1);
    const int rg = threadIdx.x >> 7;
    float acc[16];

    {
        const float bb = b1[d];
        #pragma unroll
        for (int r = 0; r < 16; ++r) acc[r] = bb;
        for (int k = 0; k < D; k += 4) {
            const float w0 = W1[(k + 0) * D + d];
            const float w1 = W1[(k + 1) * D + d];
            const float w2 = W1[(k + 2) * D + d];
            const float w3 = W1[(k + 3) * D + d];
            #pragma unroll
            for (int r = 0; r < 16; ++r) {
                const float4 h4 = *(const float4*)(sh + (rg * 16 + r) * D + k);
                acc[r] += h4.x * w0 + h4.y * w1 + h4.z * w2 + h4.w * w3;
            }
        }
        #pragma unroll
        for (int r = 0; r < 16; ++r)
            st[(rg * 16 + r) * D + d] = acc[r] > 0.0f ? acc[r] : 0.0f;
    }
    __syncthreads();

    {
        const float bb = b2[d];
        #pragma unroll
        for (int r = 0; r < 16; ++r) acc[r] = bb;
        for (int k = 0; k < D; k += 4) {
            const float w0 = W2[(k + 0) * D + d];
            const float w1 = W2[(k + 1) * D + d];
            const float w2 = W2[(k + 2) * D + d];
            const float w3 = W2[(k + 3) * D + d];
            #pragma unroll
            for (int r = 0; r < 16; ++r) {
                const float4 t4 = *(const float4*)(st + (rg * 16 + r) * D + k);
                acc[r] += t4.x * w0 + t4.y * w1 + t4.z * w2 + t4.w * w3;
            }
        }
        #pragma unroll
        for (int r = 0; r < 16; ++r) {
            const int row = row0 + rg * 16 + r;
            if (row < N) xres[(size_t)row * D + d] = acc[r];
        }
    }
}

// ---------------------------------------------------------------------------
// Stage 3: per-(graph,pocket) masked sums. 16 blocks/graph for occupancy.
// ---------------------------------------------------------------------------
#define PPARTS 16
__global__ __launch_bounds__(128) void pocket_sum_kernel(
    const float* __restrict__ xres, const float* __restrict__ pmask,
    const int* __restrict__ batch,
    float* __restrict__ psum, float* __restrict__ pcnt, int N)
{
    const int g = blockIdx.x / PPARTS;
    const int part = blockIdx.x % PPARTS;

    int lo, hi;
    {
        int l = 0, r = N;
        while (l < r) { int m = (l + r) >> 1; if (batch[m] < g) l = m + 1; else r = m; }
        lo = l;
        r = N;
        while (l < r) { int m = (l + r) >> 1; if (batch[m] < g + 1) l = m + 1; else r = m; }
        hi = l;
    }
    const int cnt = hi - lo;
    const int per = (cnt + PPARTS - 1) / PPARTS;
    const int s = lo + part * per;
    const int e = min(s + per, hi);

    const int d = threadIdx.x;
    float acc[K];
    #pragma unroll
    for (int k = 0; k < K; ++k) acc[k] = 0.0f;
    float c = 0.0f;

    for (int n = s; n < e; ++n) {
        const float xv = xres[(size_t)n * D + d];
        const float4 m0 = *(const float4*)(pmask + (size_t)n * K);
        const float4 m1 = *(const float4*)(pmask + (size_t)n * K + 4);
        acc[0] += m0.x * xv; acc[1] += m0.y * xv;
        acc[2] += m0.z * xv; acc[3] += m0.w * xv;
        acc[4] += m1.x * xv; acc[5] += m1.y * xv;
        acc[6] += m1.z * xv; acc[7] += m1.w * xv;
        if (d < K) c += pmask[(size_t)n * K + d];
    }
    #pragma unroll
    for (int k = 0; k < K; ++k)
        atomicAdd(&psum[(size_t)g * (K * D) + k * D + d], acc[k]);
    if (d < K) atomicAdd(&pcnt[g * K + d], c);
}

// ---------------------------------------------------------------------------
// Stage 4: pocket_emb = (psum / (pcnt + 1e-9)) @ Wv + bv   (per graph)
// ---------------------------------------------------------------------------
__global__ __launch_bounds__(128) void pocket_emb_kernel(
    const float* __restrict__ psum, const float* __restrict__ pcnt,
    const float* __restrict__ Wv, const float* __restrict__ bv,
    float* __restrict__ pemb)
{
    __shared__ float smean[K * D];
    __shared__ float scnt[K];
    const int g = blockIdx.x;
    const int d = threadIdx.x;
    if (d < K) scnt[d] = pcnt[g * K + d];
    __syncthreads();
    #pragma unroll
    for (int k = 0; k < K; ++k)
        smean[k * D + d] = psum[(size_t)g * (K * D) + k * D + d] / (scnt[k] + 1e-9f);
    __syncthreads();

    float acc[K];
    const float bvv = bv[d];
    #pragma unroll
    for (int k = 0; k < K; ++k) acc[k] = bvv;
    for (int j = 0; j < D; ++j) {
        const float w = Wv[j * D + d];
        #pragma unroll
        for (int k = 0; k < K; ++k) acc[k] += smean[k * D + j] * w;
    }
    #pragma unroll
    for (int k = 0; k < K; ++k)
        pemb[(size_t)g * (K * D) + k * D + d] = acc[k];
}

// ---------------------------------------------------------------------------
// Stage 5: feedback gather + LayerNorm + ReLU. One wave per node.
// ---------------------------------------------------------------------------
__global__ __launch_bounds__(256) void ln_kernel(
    const float* __restrict__ xres, const float* __restrict__ pmask,
    const int* __restrict__ batch, const float* __restrict__ pemb,
    const float* __restrict__ gamma, const float* __restrict__ beta,
    float* __restrict__ out, int N)
{
    const int wave = threadIdx.x >> 6;
    const int lane = threadIdx.x & 63;
    const int n = blockIdx.x * 4 + wave;
    if (n >= N) return;
    const int d = lane * 2;

    float2 v = *(const float2*)(xres + (size_t)n * D + d);
    const int g = batch[n];
    const float* pe = pemb + (size_t)g * (K * D);
    const float4 m0 = *(const float4*)(pmask + (size_t)n * K);
    const float4 m1 = *(const float4*)(pmask + (size_t)n * K + 4);
    const float mk[K] = {m0.x, m0.y, m0.z, m0.w, m1.x, m1.y, m1.z, m1.w};
    #pragma unroll
    for (int k = 0; k < K; ++k) {
        if (mk[k] != 0.0f) {   // wave-uniform branch (same n across the wave)
            const float2 p = *(const float2*)(pe + k * D + d);
            v.x += mk[k] * p.x;
            v.y += mk[k] * p.y;
        }
    }

    float s = v.x + v.y;
    #pragma unroll
    for (int off = 32; off; off >>= 1) s += __shfl_xor(s, off, 64);
    const float mu = s * (1.0f / 128.0f);
    const float d0 = v.x - mu, d1 = v.y - mu;
    float sq = d0 * d0 + d1 * d1;
    #pragma unroll
    for (int off = 32; off; off >>= 1) sq += __shfl_xor(sq, off, 64);
    const float var = sq * (1.0f / 128.0f);
    const float inv = rsqrtf(var + 1e-5f);

    const float2 gm = *(const float2*)(gamma + d);
    const float2 bt = *(const float2*)(beta + d);
    float y0 = d0 * inv * gm.x + bt.x;
    float y1 = d1 * inv * gm.y + bt.y;
    y0 = y0 > 0.0f ? y0 : 0.0f;
    y1 = y1 > 0.0f ? y1 : 0.0f;
    *(float2*)(out + (size_t)n * D + d) = make_float2(y0, y1);
}

// ---------------------------------------------------------------------------
extern "C" void kernel_launch(void* const* d_in, const int* in_sizes, int n_in,
                              void* d_out, int out_size, void* d_ws, size_t ws_size,
                              hipStream_t stream)
{
    const float* x     = (const float*)d_in[0];
    const int*   ei    = (const int*)  d_in[1];
    const float* ea    = (const float*)d_in[2];
    const float* pmask = (const float*)d_in[3];
    const int*   batch = (const int*)  d_in[4];
    const float* We    = (const float*)d_in[5];
    const float* be    = (const float*)d_in[6];
    const float* W1    = (const float*)d_in[7];
    const float* b1    = (const float*)d_in[8];
    const float* W2    = (const float*)d_in[9];
    const float* b2    = (const float*)d_in[10];
    const float* epsp  = (const float*)d_in[11];
    const float* gamma = (const float*)d_in[12];
    const float* beta  = (const float*)d_in[13];
    const float* Wv    = (const float*)d_in[14];
    const float* bv    = (const float*)d_in[15];
    float* out = (float*)d_out;

    const int N = in_sizes[0] / D;     // 50000
    const int E = in_sizes[1] / 2;     // 600000
    const int* src = ei;
    const int* dst = ei + E;

    float* agg  = (float*)d_ws;                       // N*D floats
    float* xres = agg  + (size_t)N * D;               // N*D floats
    float* psum = xres + (size_t)N * D;               // B*K*D
    float* pcnt = psum + (size_t)BGRAPH * K * D;      // B*K
    float* pemb = pcnt + (size_t)BGRAPH * K;          // B*K*D

    // CSR scratch aliased onto the xres region: xres is only written (never
    // read) by mlp_kernel AFTER gine_reduce has consumed these arrays.
    int* deg    = (int*)xres;                         // N
    int* offs   = deg + N;                            // N+1
    int* cursor = offs + N + 1;                       // N
    int* perm   = cursor + N;                         // E

    hipMemsetAsync(deg, 0, (size_t)N * sizeof(int), stream);
    hipMemsetAsync(psum, 0, (size_t)(BGRAPH * K * D + BGRAPH * K) * sizeof(float), stream);

    hist_kernel<<<(E + 255) / 256, 256, 0, stream>>>(dst, deg, E);
    scan_kernel<<<1, 1024, 0, stream>>>(deg, offs, cursor, N);
    scatter_kernel<<<(E + 255) / 256, 256, 0, stream>>>(dst, cursor, perm, E);
    gine_reduce_kernel<<<(N + 3) / 4, 256, 0, stream>>>(
        x, src, ea, offs, perm, We, be, agg, N);

    mlp_kernel<<<(N + MLP_RB - 1) / MLP_RB, 256, 0, stream>>>(
        x, agg, epsp, W1, b1, W2, b2, xres, N);
    pocket_sum_kernel<<<BGRAPH * PPARTS, 128, 0, stream>>>(
        xres, pmask, batch, psum, pcnt, N);
    pocket_emb_kernel<<<BGRAPH, 128, 0, stream>>>(psum, pcnt, Wv, bv, pemb);
    ln_kernel<<<(N + 3) / 4, 256, 0, stream>>>(
        xres, pmask, batch, pemb, gamma, beta, out, N);
}

// Round 3
// 491.479 us; speedup vs baseline: 1.2388x; 1.2388x over previous
//
#include <hip/hip_runtime.h>
#include <hip/hip_bf16.h>

#define D 128
#define K 8
#define BGRAPH 64

// ---------------------------------------------------------------------------
// Stage 1a: in-degree histogram over dst (4 edges/thread, int4 loads)
// ---------------------------------------------------------------------------
__global__ __launch_bounds__(256) void hist_kernel(
    const int* __restrict__ dst, int* __restrict__ deg, int E)
{
    const int i = (blockIdx.x * 256 + threadIdx.x) * 4;
    if (i + 4 <= E) {
        const int4 v = *(const int4*)(dst + i);
        atomicAdd(&deg[v.x], 1);
        atomicAdd(&deg[v.y], 1);
        atomicAdd(&deg[v.z], 1);
        atomicAdd(&deg[v.w], 1);
    } else {
        for (int j = i; j < E; ++j) atomicAdd(&deg[dst[j]], 1);
    }
}

// ---------------------------------------------------------------------------
// Stage 1b: three-phase exclusive scan of deg[N] -> offs[N+1], cursor copy.
// 1024 elements per block.
// ---------------------------------------------------------------------------
__global__ __launch_bounds__(256) void scan_partial_kernel(
    const int* __restrict__ deg, int* __restrict__ bsum, int N)
{
    const int t = threadIdx.x;
    const int base = (blockIdx.x * 256 + t) * 4;
    int s = 0;
    if (base + 4 <= N) {
        const int4 v = *(const int4*)(deg + base);
        s = v.x + v.y + v.z + v.w;
    } else {
        for (int j = base; j < N; ++j) s += deg[j];
    }
    __shared__ int red[256];
    red[t] = s;
    __syncthreads();
    for (int off = 128; off; off >>= 1) {
        if (t < off) red[t] += red[t + off];
        __syncthreads();
    }
    if (t == 0) bsum[blockIdx.x] = red[0];
}

__global__ __launch_bounds__(64) void scan_top_kernel(
    const int* __restrict__ bsum, int* __restrict__ boffs,
    int* __restrict__ offs, int nb, int N)
{
    __shared__ int sh[64];
    const int t = threadIdx.x;
    const int v = (t < nb) ? bsum[t] : 0;
    sh[t] = v;
    __syncthreads();
    for (int off = 1; off < 64; off <<= 1) {
        const int u = (t >= off) ? sh[t - off] : 0;
        __syncthreads();
        sh[t] += u;
        __syncthreads();
    }
    if (t < nb) boffs[t] = sh[t] - v;      // exclusive
    if (t == 63) offs[N] = sh[63];         // grand total
}

__global__ __launch_bounds__(256) void scan_final_kernel(
    const int* __restrict__ deg, const int* __restrict__ boffs,
    int* __restrict__ offs, int* __restrict__ cursor, int N)
{
    const int t = threadIdx.x;
    const int base = (blockIdx.x * 256 + t) * 4;
    int v0 = 0, v1 = 0, v2 = 0, v3 = 0;
    if (base + 4 <= N) {
        const int4 v = *(const int4*)(deg + base);
        v0 = v.x; v1 = v.y; v2 = v.z; v3 = v.w;
    } else {
        if (base     < N) v0 = deg[base];
        if (base + 1 < N) v1 = deg[base + 1];
        if (base + 2 < N) v2 = deg[base + 2];
        if (base + 3 < N) v3 = deg[base + 3];
    }
    const int s = v0 + v1 + v2 + v3;
    __shared__ int sh[256];
    sh[t] = s;
    __syncthreads();
    for (int off = 1; off < 256; off <<= 1) {
        const int u = (t >= off) ? sh[t - off] : 0;
        __syncthreads();
        sh[t] += u;
        __syncthreads();
    }
    int ex = boffs[blockIdx.x] + sh[t] - s;
    if (base < N)     { offs[base]     = ex; cursor[base]     = ex; } ex += v0;
    if (base + 1 < N) { offs[base + 1] = ex; cursor[base + 1] = ex; } ex += v1;
    if (base + 2 < N) { offs[base + 2] = ex; cursor[base + 2] = ex; } ex += v2;
    if (base + 3 < N) { offs[base + 3] = ex; cursor[base + 3] = ex; }
}

// ---------------------------------------------------------------------------
// Stage 1c: scatter edge ids + permuted src into dst-grouped order
// ---------------------------------------------------------------------------
__global__ __launch_bounds__(256) void scatter_kernel(
    const int* __restrict__ src, const int* __restrict__ dst,
    int* __restrict__ cursor, int* __restrict__ perm,
    int* __restrict__ src_perm, int E)
{
    const int i = blockIdx.x * 256 + threadIdx.x;
    if (i < E) {
        const int p = atomicAdd(&cursor[dst[i]], 1);
        perm[p] = i;
        src_perm[p] = src[i];
    }
}

// ---------------------------------------------------------------------------
// Stage 1d: gather-reduce, no LDS, We column in registers, 4-edge pipeline.
//   agg[n] = sum over incoming edges of relu(x[src] + ea @ We + be)
// ---------------------------------------------------------------------------
__device__ __forceinline__ void edge_acc(
    const float4& A0, const float4& A1, const float4& A2, const float4& A3,
    const float2& xv, const float2* w, const float2& bb, float2& acc)
{
    float m0 = bb.x + xv.x;
    float m1 = bb.y + xv.y;
    const float av[16] = {A0.x, A0.y, A0.z, A0.w, A1.x, A1.y, A1.z, A1.w,
                          A2.x, A2.y, A2.z, A2.w, A3.x, A3.y, A3.z, A3.w};
    #pragma unroll
    for (int j = 0; j < 16; ++j) {
        m0 += av[j] * w[j].x;
        m1 += av[j] * w[j].y;
    }
    acc.x += m0 > 0.f ? m0 : 0.f;
    acc.y += m1 > 0.f ? m1 : 0.f;
}

__global__ __launch_bounds__(256, 3) void gine_reduce_kernel(
    const float* __restrict__ x, const int* __restrict__ src_perm,
    const int* __restrict__ perm, const float* __restrict__ ea,
    const int* __restrict__ offs, const float* __restrict__ We,
    const float* __restrict__ be, float* __restrict__ agg, int N)
{
    const int wave = threadIdx.x >> 6;
    const int lane = threadIdx.x & 63;
    const int node = blockIdx.x * 4 + wave;
    if (node >= N) return;
    const int d = lane * 2;

    // This lane's two columns of We + bias, held in registers for the loop.
    float2 w[16];
    #pragma unroll
    for (int j = 0; j < 16; ++j) w[j] = *(const float2*)(We + j * D + d);
    const float2 bb = *(const float2*)(be + d);

    float2 acc = make_float2(0.f, 0.f);
    int e = offs[node];
    const int e1 = offs[node + 1];

    for (; e + 4 <= e1; e += 4) {
        // issue all loads for 4 edges up front (independent chains)
        const int i0 = perm[e],     i1 = perm[e + 1];
        const int i2 = perm[e + 2], i3 = perm[e + 3];
        const int s0 = src_perm[e],     s1 = src_perm[e + 1];
        const int s2 = src_perm[e + 2], s3 = src_perm[e + 3];
        const float2 x0 = *(const float2*)(x + (size_t)s0 * D + d);
        const float2 x1 = *(const float2*)(x + (size_t)s1 * D + d);
        const float2 x2 = *(const float2*)(x + (size_t)s2 * D + d);
        const float2 x3 = *(const float2*)(x + (size_t)s3 * D + d);
        const float4* A0 = (const float4*)(ea + (size_t)i0 * 16);
        const float4* A1 = (const float4*)(ea + (size_t)i1 * 16);
        const float4* A2 = (const float4*)(ea + (size_t)i2 * 16);
        const float4* A3 = (const float4*)(ea + (size_t)i3 * 16);
        const float4 a00 = A0[0], a01 = A0[1], a02 = A0[2], a03 = A0[3];
        const float4 a10 = A1[0], a11 = A1[1], a12 = A1[2], a13 = A1[3];
        const float4 a20 = A2[0], a21 = A2[1], a22 = A2[2], a23 = A2[3];
        const float4 a30 = A3[0], a31 = A3[1], a32 = A3[2], a33 = A3[3];

        edge_acc(a00, a01, a02, a03, x0, w, bb, acc);
        edge_acc(a10, a11, a12, a13, x1, w, bb, acc);
        edge_acc(a20, a21, a22, a23, x2, w, bb, acc);
        edge_acc(a30, a31, a32, a33, x3, w, bb, acc);
    }
    for (; e < e1; ++e) {
        const int i0 = perm[e];
        const int s0 = src_perm[e];
        const float2 x0 = *(const float2*)(x + (size_t)s0 * D + d);
        const float4* A0 = (const float4*)(ea + (size_t)i0 * 16);
        const float4 a00 = A0[0], a01 = A0[1], a02 = A0[2], a03 = A0[3];
        edge_acc(a00, a01, a02, a03, x0, w, bb, acc);
    }
    *(float2*)(agg + (size_t)node * D + d) = acc;
}

// ---------------------------------------------------------------------------
// Stage 2: fused 2-layer MLP on h = (1+eps)*x + agg
// ---------------------------------------------------------------------------
#define MLP_RB 32
__global__ __launch_bounds__(256) void mlp_kernel(
    const float* __restrict__ x, const float* __restrict__ agg,
    const float* __restrict__ epsp,
    const float* __restrict__ W1, const float* __restrict__ b1,
    const float* __restrict__ W2, const float* __restrict__ b2,
    float* __restrict__ xres, int N)
{
    __shared__ float sh[MLP_RB * D];
    __shared__ float st[MLP_RB * D];
    const int row0 = blockIdx.x * MLP_RB;
    const float ep = 1.0f + epsp[0];

    for (int i = threadIdx.x; i < MLP_RB * D / 4; i += 256) {
        const int idx = i * 4;
        const int r = idx >> 7;
        const int c = idx & (D - 1);
        const int row = row0 + r;
        float4 hv;
        if (row < N) {
            const float4 xv = *(const float4*)(x   + (size_t)row * D + c);
            const float4 av = *(const float4*)(agg + (size_t)row * D + c);
            hv = make_float4(ep * xv.x + av.x, ep * xv.y + av.y,
                             ep * xv.z + av.z, ep * xv.w + av.w);
        } else {
            hv = make_float4(0.f, 0.f, 0.f, 0.f);
        }
        *(float4*)(sh + idx) = hv;
    }
    __syncthreads();

    const int d  = threadIdx.x & (D - 1);
    const int rg = threadIdx.x >> 7;
    float acc[16];

    {
        const float bb = b1[d];
        #pragma unroll
        for (int r = 0; r < 16; ++r) acc[r] = bb;
        for (int k = 0; k < D; k += 4) {
            const float w0 = W1[(k + 0) * D + d];
            const float w1 = W1[(k + 1) * D + d];
            const float w2 = W1[(k + 2) * D + d];
            const float w3 = W1[(k + 3) * D + d];
            #pragma unroll
            for (int r = 0; r < 16; ++r) {
                const float4 h4 = *(const float4*)(sh + (rg * 16 + r) * D + k);
                acc[r] += h4.x * w0 + h4.y * w1 + h4.z * w2 + h4.w * w3;
            }
        }
        #pragma unroll
        for (int r = 0; r < 16; ++r)
            st[(rg * 16 + r) * D + d] = acc[r] > 0.0f ? acc[r] : 0.0f;
    }
    __syncthreads();

    {
        const float bb = b2[d];
        #pragma unroll
        for (int r = 0; r < 16; ++r) acc[r] = bb;
        for (int k = 0; k < D; k += 4) {
            const float w0 = W2[(k + 0) * D + d];
            const float w1 = W2[(k + 1) * D + d];
            const float w2 = W2[(k + 2) * D + d];
            const float w3 = W2[(k + 3) * D + d];
            #pragma unroll
            for (int r = 0; r < 16; ++r) {
                const float4 t4 = *(const float4*)(st + (rg * 16 + r) * D + k);
                acc[r] += t4.x * w0 + t4.y * w1 + t4.z * w2 + t4.w * w3;
            }
        }
        #pragma unroll
        for (int r = 0; r < 16; ++r) {
            const int row = row0 + rg * 16 + r;
            if (row < N) xres[(size_t)row * D + d] = acc[r];
        }
    }
}

// ---------------------------------------------------------------------------
// Stage 3: per-(graph,pocket) masked sums
// ---------------------------------------------------------------------------
#define PPARTS 16
__global__ __launch_bounds__(128) void pocket_sum_kernel(
    const float* __restrict__ xres, const float* __restrict__ pmask,
    const int* __restrict__ batch,
    float* __restrict__ psum, float* __restrict__ pcnt, int N)
{
    const int g = blockIdx.x / PPARTS;
    const int part = blockIdx.x % PPARTS;

    int lo, hi;
    {
        int l = 0, r = N;
        while (l < r) { int m = (l + r) >> 1; if (batch[m] < g) l = m + 1; else r = m; }
        lo = l;
        r = N;
        while (l < r) { int m = (l + r) >> 1; if (batch[m] < g + 1) l = m + 1; else r = m; }
        hi = l;
    }
    const int cnt = hi - lo;
    const int per = (cnt + PPARTS - 1) / PPARTS;
    const int s = lo + part * per;
    const int e = min(s + per, hi);

    const int d = threadIdx.x;
    float acc[K];
    #pragma unroll
    for (int k = 0; k < K; ++k) acc[k] = 0.0f;
    float c = 0.0f;

    for (int n = s; n < e; ++n) {
        const float xv = xres[(size_t)n * D + d];
        const float4 m0 = *(const float4*)(pmask + (size_t)n * K);
        const float4 m1 = *(const float4*)(pmask + (size_t)n * K + 4);
        acc[0] += m0.x * xv; acc[1] += m0.y * xv;
        acc[2] += m0.z * xv; acc[3] += m0.w * xv;
        acc[4] += m1.x * xv; acc[5] += m1.y * xv;
        acc[6] += m1.z * xv; acc[7] += m1.w * xv;
        if (d < K) c += pmask[(size_t)n * K + d];
    }
    #pragma unroll
    for (int k = 0; k < K; ++k)
        atomicAdd(&psum[(size_t)g * (K * D) + k * D + d], acc[k]);
    if (d < K) atomicAdd(&pcnt[g * K + d], c);
}

// ---------------------------------------------------------------------------
// Stage 4: pocket_emb = (psum / (pcnt + 1e-9)) @ Wv + bv
// ---------------------------------------------------------------------------
__global__ __launch_bounds__(128) void pocket_emb_kernel(
    const float* __restrict__ psum, const float* __restrict__ pcnt,
    const float* __restrict__ Wv, const float* __restrict__ bv,
    float* __restrict__ pemb)
{
    __shared__ float smean[K * D];
    __shared__ float scnt[K];
    const int g = blockIdx.x;
    const int d = threadIdx.x;
    if (d < K) scnt[d] = pcnt[g * K + d];
    __syncthreads();
    #pragma unroll
    for (int k = 0; k < K; ++k)
        smean[k * D + d] = psum[(size_t)g * (K * D) + k * D + d] / (scnt[k] + 1e-9f);
    __syncthreads();

    float acc[K];
    const float bvv = bv[d];
    #pragma unroll
    for (int k = 0; k < K; ++k) acc[k] = bvv;
    for (int j = 0; j < D; ++j) {
        const float w = Wv[j * D + d];
        #pragma unroll
        for (int k = 0; k < K; ++k) acc[k] += smean[k * D + j] * w;
    }
    #pragma unroll
    for (int k = 0; k < K; ++k)
        pemb[(size_t)g * (K * D) + k * D + d] = acc[k];
}

// ---------------------------------------------------------------------------
// Stage 5: feedback gather + LayerNorm + ReLU. One wave per node.
// ---------------------------------------------------------------------------
__global__ __launch_bounds__(256) void ln_kernel(
    const float* __restrict__ xres, const float* __restrict__ pmask,
    const int* __restrict__ batch, const float* __restrict__ pemb,
    const float* __restrict__ gamma, const float* __restrict__ beta,
    float* __restrict__ out, int N)
{
    const int wave = threadIdx.x >> 6;
    const int lane = threadIdx.x & 63;
    const int n = blockIdx.x * 4 + wave;
    if (n >= N) return;
    const int d = lane * 2;

    float2 v = *(const float2*)(xres + (size_t)n * D + d);
    const int g = batch[n];
    const float* pe = pemb + (size_t)g * (K * D);
    const float4 m0 = *(const float4*)(pmask + (size_t)n * K);
    const float4 m1 = *(const float4*)(pmask + (size_t)n * K + 4);
    const float mk[K] = {m0.x, m0.y, m0.z, m0.w, m1.x, m1.y, m1.z, m1.w};
    #pragma unroll
    for (int k = 0; k < K; ++k) {
        if (mk[k] != 0.0f) {   // wave-uniform branch
            const float2 p = *(const float2*)(pe + k * D + d);
            v.x += mk[k] * p.x;
            v.y += mk[k] * p.y;
        }
    }

    float s = v.x + v.y;
    #pragma unroll
    for (int off = 32; off; off >>= 1) s += __shfl_xor(s, off, 64);
    const float mu = s * (1.0f / 128.0f);
    const float d0 = v.x - mu, d1 = v.y - mu;
    float sq = d0 * d0 + d1 * d1;
    #pragma unroll
    for (int off = 32; off; off >>= 1) sq += __shfl_xor(sq, off, 64);
    const float var = sq * (1.0f / 128.0f);
    const float inv = rsqrtf(var + 1e-5f);

    const float2 gm = *(const float2*)(gamma + d);
    const float2 bt = *(const float2*)(beta + d);
    float y0 = d0 * inv * gm.x + bt.x;
    float y1 = d1 * inv * gm.y + bt.y;
    y0 = y0 > 0.0f ? y0 : 0.0f;
    y1 = y1 > 0.0f ? y1 : 0.0f;
    *(float2*)(out + (size_t)n * D + d) = make_float2(y0, y1);
}

// ---------------------------------------------------------------------------
extern "C" void kernel_launch(void* const* d_in, const int* in_sizes, int n_in,
                              void* d_out, int out_size, void* d_ws, size_t ws_size,
                              hipStream_t stream)
{
    const float* x     = (const float*)d_in[0];
    const int*   ei    = (const int*)  d_in[1];
    const float* ea    = (const float*)d_in[2];
    const float* pmask = (const float*)d_in[3];
    const int*   batch = (const int*)  d_in[4];
    const float* We    = (const float*)d_in[5];
    const float* be    = (const float*)d_in[6];
    const float* W1    = (const float*)d_in[7];
    const float* b1    = (const float*)d_in[8];
    const float* W2    = (const float*)d_in[9];
    const float* b2    = (const float*)d_in[10];
    const float* epsp  = (const float*)d_in[11];
    const float* gamma = (const float*)d_in[12];
    const float* beta  = (const float*)d_in[13];
    const float* Wv    = (const float*)d_in[14];
    const float* bv    = (const float*)d_in[15];
    float* out = (float*)d_out;

    const int N = in_sizes[0] / D;     // 50000
    const int E = in_sizes[1] / 2;     // 600000
    const int* src = ei;
    const int* dst = ei + E;

    float* agg  = (float*)d_ws;                       // N*D floats
    float* xres = agg  + (size_t)N * D;               // N*D floats
    float* psum = xres + (size_t)N * D;               // B*K*D
    float* pcnt = psum + (size_t)BGRAPH * K * D;      // B*K
    float* pemb = pcnt + (size_t)BGRAPH * K;          // B*K*D
    float* extra = pemb + (size_t)BGRAPH * K * D;     // small scan scratch

    // CSR scratch aliased onto the xres region (xres written only after all
    // CSR consumers are done): deg, offs, cursor, perm, src_perm.
    int* deg      = (int*)xres;                       // N
    int* offs     = deg + N;                          // N+1
    int* cursor   = offs + N + 1;                     // N
    int* perm     = cursor + N;                       // E
    int* src_perm = perm + E;                         // E
    int* bsum     = (int*)extra;                      // 64
    int* boffs    = bsum + 64;                        // 64

    const int nb = (N + 1023) / 1024;                 // scan blocks (49)

    hipMemsetAsync(deg, 0, (size_t)N * sizeof(int), stream);
    hipMemsetAsync(psum, 0, (size_t)(BGRAPH * K * D + BGRAPH * K) * sizeof(float), stream);

    hist_kernel<<<(E / 4 + 255) / 256, 256, 0, stream>>>(dst, deg, E);
    scan_partial_kernel<<<nb, 256, 0, stream>>>(deg, bsum, N);
    scan_top_kernel<<<1, 64, 0, stream>>>(bsum, boffs, offs, nb, N);
    scan_final_kernel<<<nb, 256, 0, stream>>>(deg, boffs, offs, cursor, N);
    scatter_kernel<<<(E + 255) / 256, 256, 0, stream>>>(
        src, dst, cursor, perm, src_perm, E);
    gine_reduce_kernel<<<(N + 3) / 4, 256, 0, stream>>>(
        x, src_perm, perm, ea, offs, We, be, agg, N);

    mlp_kernel<<<(N + MLP_RB - 1) / MLP_RB, 256, 0, stream>>>(
        x, agg, epsp, W1, b1, W2, b2, xres, N);
    pocket_sum_kernel<<<BGRAPH * PPARTS, 128, 0, stream>>>(
        xres, pmask, batch, psum, pcnt, N);
    pocket_emb_kernel<<<BGRAPH, 128, 0, stream>>>(psum, pcnt, Wv, bv, pemb);
    ln_kernel<<<(N + 3) / 4, 256, 0, stream>>>(
        xres, pmask, batch, pemb, gamma, beta, out, N);
}

// Round 4
// 455.095 us; speedup vs baseline: 1.3378x; 1.0799x over previous
//
#include <hip/hip_runtime.h>
#include <hip/hip_bf16.h>

#define D 128
#define K 8
#define BGRAPH 64
#define CH 64   // edges per wave in gine_reduce

// ---------------------------------------------------------------------------
// Stage 1a: in-degree histogram over dst (4 edges/thread, int4 loads)
// ---------------------------------------------------------------------------
__global__ __launch_bounds__(256) void hist_kernel(
    const int* __restrict__ dst, int* __restrict__ deg, int E)
{
    const int i = (blockIdx.x * 256 + threadIdx.x) * 4;
    if (i + 4 <= E) {
        const int4 v = *(const int4*)(dst + i);
        atomicAdd(&deg[v.x], 1);
        atomicAdd(&deg[v.y], 1);
        atomicAdd(&deg[v.z], 1);
        atomicAdd(&deg[v.w], 1);
    } else {
        for (int j = i; j < E; ++j) atomicAdd(&deg[dst[j]], 1);
    }
}

// ---------------------------------------------------------------------------
// Stage 1b: three-phase exclusive scan of deg[N] -> offs[N+1], cursor copy.
// ---------------------------------------------------------------------------
__global__ __launch_bounds__(256) void scan_partial_kernel(
    const int* __restrict__ deg, int* __restrict__ bsum, int N)
{
    const int t = threadIdx.x;
    const int base = (blockIdx.x * 256 + t) * 4;
    int s = 0;
    if (base + 4 <= N) {
        const int4 v = *(const int4*)(deg + base);
        s = v.x + v.y + v.z + v.w;
    } else {
        for (int j = base; j < N; ++j) s += deg[j];
    }
    __shared__ int red[256];
    red[t] = s;
    __syncthreads();
    for (int off = 128; off; off >>= 1) {
        if (t < off) red[t] += red[t + off];
        __syncthreads();
    }
    if (t == 0) bsum[blockIdx.x] = red[0];
}

__global__ __launch_bounds__(64) void scan_top_kernel(
    const int* __restrict__ bsum, int* __restrict__ boffs,
    int* __restrict__ offs, int nb, int N)
{
    __shared__ int sh[64];
    const int t = threadIdx.x;
    const int v = (t < nb) ? bsum[t] : 0;
    sh[t] = v;
    __syncthreads();
    for (int off = 1; off < 64; off <<= 1) {
        const int u = (t >= off) ? sh[t - off] : 0;
        __syncthreads();
        sh[t] += u;
        __syncthreads();
    }
    if (t < nb) boffs[t] = sh[t] - v;      // exclusive
    if (t == 63) offs[N] = sh[63];         // grand total
}

__global__ __launch_bounds__(256) void scan_final_kernel(
    const int* __restrict__ deg, const int* __restrict__ boffs,
    int* __restrict__ offs, int* __restrict__ cursor, int N)
{
    const int t = threadIdx.x;
    const int base = (blockIdx.x * 256 + t) * 4;
    int v0 = 0, v1 = 0, v2 = 0, v3 = 0;
    if (base + 4 <= N) {
        const int4 v = *(const int4*)(deg + base);
        v0 = v.x; v1 = v.y; v2 = v.z; v3 = v.w;
    } else {
        if (base     < N) v0 = deg[base];
        if (base + 1 < N) v1 = deg[base + 1];
        if (base + 2 < N) v2 = deg[base + 2];
        if (base + 3 < N) v3 = deg[base + 3];
    }
    const int s = v0 + v1 + v2 + v3;
    __shared__ int sh[256];
    sh[t] = s;
    __syncthreads();
    for (int off = 1; off < 256; off <<= 1) {
        const int u = (t >= off) ? sh[t - off] : 0;
        __syncthreads();
        sh[t] += u;
        __syncthreads();
    }
    int ex = boffs[blockIdx.x] + sh[t] - s;
    if (base < N)     { offs[base]     = ex; cursor[base]     = ex; } ex += v0;
    if (base + 1 < N) { offs[base + 1] = ex; cursor[base + 1] = ex; } ex += v1;
    if (base + 2 < N) { offs[base + 2] = ex; cursor[base + 2] = ex; } ex += v2;
    if (base + 3 < N) { offs[base + 3] = ex; cursor[base + 3] = ex; }
}

// ---------------------------------------------------------------------------
// Stage 1c: scatter edge id + src + dst into dst-grouped order
// ---------------------------------------------------------------------------
__global__ __launch_bounds__(256) void scatter_kernel(
    const int* __restrict__ src, const int* __restrict__ dst,
    int* __restrict__ cursor, int* __restrict__ perm,
    int* __restrict__ src_perm, int* __restrict__ dst_perm, int E)
{
    const int i = blockIdx.x * 256 + threadIdx.x;
    if (i < E) {
        const int dv = dst[i];
        const int p = atomicAdd(&cursor[dv], 1);
        perm[p] = i;
        src_perm[p] = src[i];
        dst_perm[p] = dv;
    }
}

// ---------------------------------------------------------------------------
// Stage 1d: EDGE-PARALLEL gather-reduce over dst-sorted edges.
// One wave per CH consecutive edges; per-lane coalesced metadata load,
// shfl-broadcast per edge; segmented register accumulation; interior nodes
// flushed with a plain store, chunk-boundary nodes with atomicAdd.
// Requires agg pre-zeroed.
// ---------------------------------------------------------------------------
__device__ __forceinline__ void flush_row(
    float* __restrict__ agg, int node, int d, float2 acc, int first, int last)
{
    float* p = agg + (size_t)node * D + d;
    if (node == first || node == last) {
        if (acc.x != 0.f) atomicAdd(p,     acc.x);
        if (acc.y != 0.f) atomicAdd(p + 1, acc.y);
    } else {
        *(float2*)p = acc;
    }
}

__global__ __launch_bounds__(256) void gine_reduce_kernel(
    const float* __restrict__ x, const int* __restrict__ src_perm,
    const int* __restrict__ dst_perm, const int* __restrict__ perm,
    const float* __restrict__ ea, const float* __restrict__ We,
    const float* __restrict__ be, float* __restrict__ agg, int E)
{
    const int wave = threadIdx.x >> 6;
    const int lane = threadIdx.x & 63;
    const int chunk = blockIdx.x * 4 + wave;
    const int e0 = chunk * CH;
    if (e0 >= E) return;
    const int kmax = min(CH, E - e0);
    const int d = lane * 2;

    // this lane's two columns of We + bias in registers
    float2 w[16];
    #pragma unroll
    for (int j = 0; j < 16; ++j) w[j] = *(const float2*)(We + j * D + d);
    const float2 bb = *(const float2*)(be + d);

    // coalesced per-lane edge metadata
    const int li = e0 + min(lane, kmax - 1);
    const int my_src = src_perm[li];
    const int my_dst = dst_perm[li];
    const int my_eid = perm[li];

    const int first = __shfl(my_dst, 0);
    const int last  = __shfl(my_dst, kmax - 1);

    // pipeline prologue: edge 0
    int sk = __shfl(my_src, 0);
    int dk = __shfl(my_dst, 0);
    int ek = __shfl(my_eid, 0);
    float2 xv = *(const float2*)(x + (size_t)sk * D + d);
    const float4* A = (const float4*)(ea + (size_t)ek * 16);
    float4 a0 = A[0], a1 = A[1], a2 = A[2], a3 = A[3];

    float2 acc = make_float2(0.f, 0.f);
    int cur = dk;

    for (int k = 0; k < kmax; ++k) {
        // prefetch edge k+1
        int nsk = 0, ndk = 0, nek = 0;
        float2 nxv = make_float2(0.f, 0.f);
        float4 na0 = {}, na1 = {}, na2 = {}, na3 = {};
        if (k + 1 < kmax) {
            nsk = __shfl(my_src, k + 1);
            ndk = __shfl(my_dst, k + 1);
            nek = __shfl(my_eid, k + 1);
            nxv = *(const float2*)(x + (size_t)nsk * D + d);
            const float4* NA = (const float4*)(ea + (size_t)nek * 16);
            na0 = NA[0]; na1 = NA[1]; na2 = NA[2]; na3 = NA[3];
        }

        if (dk != cur) {                 // wave-uniform (dk is broadcast)
            flush_row(agg, cur, d, acc, first, last);
            acc = make_float2(0.f, 0.f);
            cur = dk;
        }

        // message for edge k
        float m0 = bb.x + xv.x;
        float m1 = bb.y + xv.y;
        const float av[16] = {a0.x, a0.y, a0.z, a0.w, a1.x, a1.y, a1.z, a1.w,
                              a2.x, a2.y, a2.z, a2.w, a3.x, a3.y, a3.z, a3.w};
        #pragma unroll
        for (int j = 0; j < 16; ++j) {
            m0 += av[j] * w[j].x;
            m1 += av[j] * w[j].y;
        }
        acc.x += m0 > 0.f ? m0 : 0.f;
        acc.y += m1 > 0.f ? m1 : 0.f;

        // rotate pipeline
        sk = nsk; dk = ndk; ek = nek; xv = nxv;
        a0 = na0; a1 = na1; a2 = na2; a3 = na3;
    }
    flush_row(agg, cur, d, acc, first, last);
}

// ---------------------------------------------------------------------------
// Stage 2: fused 2-layer MLP on h = (1+eps)*x + agg
// 48-row tile, 192 threads, thread = 4 rows x 8 cols; LDS stride 132
// (row-stride mod 32 banks = 4 -> only 2-way aliasing on reads, free).
// ---------------------------------------------------------------------------
#define MT_ROWS 48
#define SH_STR  132
__global__ __launch_bounds__(192) void mlp_kernel(
    const float* __restrict__ x, const float* __restrict__ agg,
    const float* __restrict__ epsp,
    const float* __restrict__ W1, const float* __restrict__ b1,
    const float* __restrict__ W2, const float* __restrict__ b2,
    float* __restrict__ xres, int N)
{
    __shared__ float sh[MT_ROWS * SH_STR];   // 25.3 KB
    __shared__ float st[MT_ROWS * SH_STR];   // 25.3 KB
    const int row0 = blockIdx.x * MT_ROWS;
    const float ep = 1.0f + epsp[0];

    // stage h tile (float4 coalesced global reads)
    for (int i = threadIdx.x; i < MT_ROWS * D / 4; i += 192) {
        const int flat = i * 4;
        const int r = flat >> 7;
        const int c = flat & (D - 1);
        const int row = row0 + r;
        float4 hv;
        if (row < N) {
            const float4 xv = *(const float4*)(x   + (size_t)row * D + c);
            const float4 av = *(const float4*)(agg + (size_t)row * D + c);
            hv = make_float4(ep * xv.x + av.x, ep * xv.y + av.y,
                             ep * xv.z + av.z, ep * xv.w + av.w);
        } else {
            hv = make_float4(0.f, 0.f, 0.f, 0.f);
        }
        *(float4*)(sh + r * SH_STR + c) = hv;
    }
    __syncthreads();

    const int cg = (threadIdx.x & 15) * 8;   // 8 output cols
    const int rg = (threadIdx.x >> 4) * 4;   // 4 rows

    float acc[4][8];

    // ---- layer 1: t = relu(h @ W1 + b1) ----
    {
        const float4 bA = *(const float4*)(b1 + cg);
        const float4 bB = *(const float4*)(b1 + cg + 4);
        #pragma unroll
        for (int r = 0; r < 4; ++r) {
            acc[r][0] = bA.x; acc[r][1] = bA.y; acc[r][2] = bA.z; acc[r][3] = bA.w;
            acc[r][4] = bB.x; acc[r][5] = bB.y; acc[r][6] = bB.z; acc[r][7] = bB.w;
        }
        for (int k = 0; k < D; k += 4) {
            float wv[4][8];
            #pragma unroll
            for (int kk = 0; kk < 4; ++kk) {
                const float4 wa = *(const float4*)(W1 + (size_t)(k + kk) * D + cg);
                const float4 wb = *(const float4*)(W1 + (size_t)(k + kk) * D + cg + 4);
                wv[kk][0] = wa.x; wv[kk][1] = wa.y; wv[kk][2] = wa.z; wv[kk][3] = wa.w;
                wv[kk][4] = wb.x; wv[kk][5] = wb.y; wv[kk][6] = wb.z; wv[kk][7] = wb.w;
            }
            #pragma unroll
            for (int r = 0; r < 4; ++r) {
                const float4 h4 = *(const float4*)(sh + (rg + r) * SH_STR + k);
                const float hk[4] = {h4.x, h4.y, h4.z, h4.w};
                #pragma unroll
                for (int kk = 0; kk < 4; ++kk)
                    #pragma unroll
                    for (int c = 0; c < 8; ++c)
                        acc[r][c] += hk[kk] * wv[kk][c];
            }
        }
        #pragma unroll
        for (int r = 0; r < 4; ++r) {
            float4 oa, ob;
            oa.x = acc[r][0] > 0.f ? acc[r][0] : 0.f;
            oa.y = acc[r][1] > 0.f ? acc[r][1] : 0.f;
            oa.z = acc[r][2] > 0.f ? acc[r][2] : 0.f;
            oa.w = acc[r][3] > 0.f ? acc[r][3] : 0.f;
            ob.x = acc[r][4] > 0.f ? acc[r][4] : 0.f;
            ob.y = acc[r][5] > 0.f ? acc[r][5] : 0.f;
            ob.z = acc[r][6] > 0.f ? acc[r][6] : 0.f;
            ob.w = acc[r][7] > 0.f ? acc[r][7] : 0.f;
            *(float4*)(st + (rg + r) * SH_STR + cg)     = oa;
            *(float4*)(st + (rg + r) * SH_STR + cg + 4) = ob;
        }
    }
    __syncthreads();

    // ---- layer 2: x_res = t @ W2 + b2 ----
    {
        const float4 bA = *(const float4*)(b2 + cg);
        const float4 bB = *(const float4*)(b2 + cg + 4);
        #pragma unroll
        for (int r = 0; r < 4; ++r) {
            acc[r][0] = bA.x; acc[r][1] = bA.y; acc[r][2] = bA.z; acc[r][3] = bA.w;
            acc[r][4] = bB.x; acc[r][5] = bB.y; acc[r][6] = bB.z; acc[r][7] = bB.w;
        }
        for (int k = 0; k < D; k += 4) {
            float wv[4][8];
            #pragma unroll
            for (int kk = 0; kk < 4; ++kk) {
                const float4 wa = *(const float4*)(W2 + (size_t)(k + kk) * D + cg);
                const float4 wb = *(const float4*)(W2 + (size_t)(k + kk) * D + cg + 4);
                wv[kk][0] = wa.x; wv[kk][1] = wa.y; wv[kk][2] = wa.z; wv[kk][3] = wa.w;
                wv[kk][4] = wb.x; wv[kk][5] = wb.y; wv[kk][6] = wb.z; wv[kk][7] = wb.w;
            }
            #pragma unroll
            for (int r = 0; r < 4; ++r) {
                const float4 h4 = *(const float4*)(st + (rg + r) * SH_STR + k);
                const float hk[4] = {h4.x, h4.y, h4.z, h4.w};
                #pragma unroll
                for (int kk = 0; kk < 4; ++kk)
                    #pragma unroll
                    for (int c = 0; c < 8; ++c)
                        acc[r][c] += hk[kk] * wv[kk][c];
            }
        }
        #pragma unroll
        for (int r = 0; r < 4; ++r) {
            const int row = row0 + rg + r;
            if (row < N) {
                *(float4*)(xres + (size_t)row * D + cg) =
                    make_float4(acc[r][0], acc[r][1], acc[r][2], acc[r][3]);
                *(float4*)(xres + (size_t)row * D + cg + 4) =
                    make_float4(acc[r][4], acc[r][5], acc[r][6], acc[r][7]);
            }
        }
    }
}

// ---------------------------------------------------------------------------
// Stage 3: per-(graph,pocket) masked sums
// ---------------------------------------------------------------------------
#define PPARTS 32
__global__ __launch_bounds__(128) void pocket_sum_kernel(
    const float* __restrict__ xres, const float* __restrict__ pmask,
    const int* __restrict__ batch,
    float* __restrict__ psum, float* __restrict__ pcnt, int N)
{
    const int g = blockIdx.x / PPARTS;
    const int part = blockIdx.x % PPARTS;

    int lo, hi;
    {
        int l = 0, r = N;
        while (l < r) { int m = (l + r) >> 1; if (batch[m] < g) l = m + 1; else r = m; }
        lo = l;
        r = N;
        while (l < r) { int m = (l + r) >> 1; if (batch[m] < g + 1) l = m + 1; else r = m; }
        hi = l;
    }
    const int cnt = hi - lo;
    const int per = (cnt + PPARTS - 1) / PPARTS;
    const int s = lo + part * per;
    const int e = min(s + per, hi);

    const int d = threadIdx.x;
    float acc[K];
    #pragma unroll
    for (int k = 0; k < K; ++k) acc[k] = 0.0f;
    float c = 0.0f;

    for (int n = s; n < e; ++n) {
        const float xv = xres[(size_t)n * D + d];
        const float4 m0 = *(const float4*)(pmask + (size_t)n * K);
        const float4 m1 = *(const float4*)(pmask + (size_t)n * K + 4);
        acc[0] += m0.x * xv; acc[1] += m0.y * xv;
        acc[2] += m0.z * xv; acc[3] += m0.w * xv;
        acc[4] += m1.x * xv; acc[5] += m1.y * xv;
        acc[6] += m1.z * xv; acc[7] += m1.w * xv;
        if (d < K) c += pmask[(size_t)n * K + d];
    }
    #pragma unroll
    for (int k = 0; k < K; ++k)
        atomicAdd(&psum[(size_t)g * (K * D) + k * D + d], acc[k]);
    if (d < K) atomicAdd(&pcnt[g * K + d], c);
}

// ---------------------------------------------------------------------------
// Stage 4: pocket_emb = (psum / (pcnt + 1e-9)) @ Wv + bv
// ---------------------------------------------------------------------------
__global__ __launch_bounds__(128) void pocket_emb_kernel(
    const float* __restrict__ psum, const float* __restrict__ pcnt,
    const float* __restrict__ Wv, const float* __restrict__ bv,
    float* __restrict__ pemb)
{
    __shared__ float smean[K * D];
    __shared__ float scnt[K];
    const int g = blockIdx.x;
    const int d = threadIdx.x;
    if (d < K) scnt[d] = pcnt[g * K + d];
    __syncthreads();
    #pragma unroll
    for (int k = 0; k < K; ++k)
        smean[k * D + d] = psum[(size_t)g * (K * D) + k * D + d] / (scnt[k] + 1e-9f);
    __syncthreads();

    float acc[K];
    const float bvv = bv[d];
    #pragma unroll
    for (int k = 0; k < K; ++k) acc[k] = bvv;
    for (int j = 0; j < D; ++j) {
        const float w = Wv[j * D + d];
        #pragma unroll
        for (int k = 0; k < K; ++k) acc[k] += smean[k * D + j] * w;
    }
    #pragma unroll
    for (int k = 0; k < K; ++k)
        pemb[(size_t)g * (K * D) + k * D + d] = acc[k];
}

// ---------------------------------------------------------------------------
// Stage 5: feedback gather + LayerNorm + ReLU. One wave per node.
// ---------------------------------------------------------------------------
__global__ __launch_bounds__(256) void ln_kernel(
    const float* __restrict__ xres, const float* __restrict__ pmask,
    const int* __restrict__ batch, const float* __restrict__ pemb,
    const float* __restrict__ gamma, const float* __restrict__ beta,
    float* __restrict__ out, int N)
{
    const int wave = threadIdx.x >> 6;
    const int lane = threadIdx.x & 63;
    const int n = blockIdx.x * 4 + wave;
    if (n >= N) return;
    const int d = lane * 2;

    float2 v = *(const float2*)(xres + (size_t)n * D + d);
    const int g = batch[n];
    const float* pe = pemb + (size_t)g * (K * D);
    const float4 m0 = *(const float4*)(pmask + (size_t)n * K);
    const float4 m1 = *(const float4*)(pmask + (size_t)n * K + 4);
    const float mk[K] = {m0.x, m0.y, m0.z, m0.w, m1.x, m1.y, m1.z, m1.w};
    #pragma unroll
    for (int k = 0; k < K; ++k) {
        if (mk[k] != 0.0f) {   // wave-uniform branch
            const float2 p = *(const float2*)(pe + k * D + d);
            v.x += mk[k] * p.x;
            v.y += mk[k] * p.y;
        }
    }

    float s = v.x + v.y;
    #pragma unroll
    for (int off = 32; off; off >>= 1) s += __shfl_xor(s, off, 64);
    const float mu = s * (1.0f / 128.0f);
    const float d0 = v.x - mu, d1 = v.y - mu;
    float sq = d0 * d0 + d1 * d1;
    #pragma unroll
    for (int off = 32; off; off >>= 1) sq += __shfl_xor(sq, off, 64);
    const float var = sq * (1.0f / 128.0f);
    const float inv = rsqrtf(var + 1e-5f);

    const float2 gm = *(const float2*)(gamma + d);
    const float2 bt = *(const float2*)(beta + d);
    float y0 = d0 * inv * gm.x + bt.x;
    float y1 = d1 * inv * gm.y + bt.y;
    y0 = y0 > 0.0f ? y0 : 0.0f;
    y1 = y1 > 0.0f ? y1 : 0.0f;
    *(float2*)(out + (size_t)n * D + d) = make_float2(y0, y1);
}

// ---------------------------------------------------------------------------
extern "C" void kernel_launch(void* const* d_in, const int* in_sizes, int n_in,
                              void* d_out, int out_size, void* d_ws, size_t ws_size,
                              hipStream_t stream)
{
    const float* x     = (const float*)d_in[0];
    const int*   ei    = (const int*)  d_in[1];
    const float* ea    = (const float*)d_in[2];
    const float* pmask = (const float*)d_in[3];
    const int*   batch = (const int*)  d_in[4];
    const float* We    = (const float*)d_in[5];
    const float* be    = (const float*)d_in[6];
    const float* W1    = (const float*)d_in[7];
    const float* b1    = (const float*)d_in[8];
    const float* W2    = (const float*)d_in[9];
    const float* b2    = (const float*)d_in[10];
    const float* epsp  = (const float*)d_in[11];
    const float* gamma = (const float*)d_in[12];
    const float* beta  = (const float*)d_in[13];
    const float* Wv    = (const float*)d_in[14];
    const float* bv    = (const float*)d_in[15];
    float* out = (float*)d_out;

    const int N = in_sizes[0] / D;     // 50000
    const int E = in_sizes[1] / 2;     // 600000
    const int* src = ei;
    const int* dst = ei + E;

    float* agg  = (float*)d_ws;                       // N*D floats
    float* xres = agg  + (size_t)N * D;               // N*D floats
    float* psum = xres + (size_t)N * D;               // B*K*D
    float* pcnt = psum + (size_t)BGRAPH * K * D;      // B*K
    float* pemb = pcnt + (size_t)BGRAPH * K;          // B*K*D
    float* extra = pemb + (size_t)BGRAPH * K * D;     // small scan scratch

    // CSR scratch aliased onto the xres region (fully consumed before
    // mlp_kernel writes xres).
    int* deg      = (int*)xres;                       // N
    int* offs     = deg + N;                          // N+1
    int* cursor   = offs + N + 1;                     // N
    int* perm     = cursor + N;                       // E
    int* src_perm = perm + E;                         // E
    int* dst_perm = src_perm + E;                     // E
    int* bsum     = (int*)extra;                      // 64
    int* boffs    = bsum + 64;                        // 64

    const int nb = (N + 1023) / 1024;                 // scan blocks (49)
    const int nchunks = (E + CH - 1) / CH;            // 9375

    hipMemsetAsync(deg, 0, (size_t)N * sizeof(int), stream);
    hipMemsetAsync(agg, 0, (size_t)N * D * sizeof(float), stream);
    hipMemsetAsync(psum, 0, (size_t)(BGRAPH * K * D + BGRAPH * K) * sizeof(float), stream);

    hist_kernel<<<(E / 4 + 255) / 256, 256, 0, stream>>>(dst, deg, E);
    scan_partial_kernel<<<nb, 256, 0, stream>>>(deg, bsum, N);
    scan_top_kernel<<<1, 64, 0, stream>>>(bsum, boffs, offs, nb, N);
    scan_final_kernel<<<nb, 256, 0, stream>>>(deg, boffs, offs, cursor, N);
    scatter_kernel<<<(E + 255) / 256, 256, 0, stream>>>(
        src, dst, cursor, perm, src_perm, dst_perm, E);
    gine_reduce_kernel<<<(nchunks + 3) / 4, 256, 0, stream>>>(
        x, src_perm, dst_perm, perm, ea, We, be, agg, E);

    mlp_kernel<<<(N + MT_ROWS - 1) / MT_ROWS, 192, 0, stream>>>(
        x, agg, epsp, W1, b1, W2, b2, xres, N);
    pocket_sum_kernel<<<BGRAPH * PPARTS, 128, 0, stream>>>(
        xres, pmask, batch, psum, pcnt, N);
    pocket_emb_kernel<<<BGRAPH, 128, 0, stream>>>(psum, pcnt, Wv, bv, pemb);
    ln_kernel<<<(N + 3) / 4, 256, 0, stream>>>(
        xres, pmask, batch, pemb, gamma, beta, out, N);
}

// Round 5
// 409.152 us; speedup vs baseline: 1.4881x; 1.1123x over previous
//
#include <hip/hip_runtime.h>
#include <hip/hip_bf16.h>
#include <stdint.h>

#define D 128
#define K 8
#define BGRAPH 64
#define CH 64   // edges per wave in gine_reduce

// ---------------------------------------------------------------------------
// Stage 1a: in-degree histogram over dst (4 edges/thread, int4 loads)
// ---------------------------------------------------------------------------
__global__ __launch_bounds__(256) void hist_kernel(
    const int* __restrict__ dst, int* __restrict__ deg, int E)
{
    const int i = (blockIdx.x * 256 + threadIdx.x) * 4;
    if (i + 4 <= E) {
        const int4 v = *(const int4*)(dst + i);
        atomicAdd(&deg[v.x], 1);
        atomicAdd(&deg[v.y], 1);
        atomicAdd(&deg[v.z], 1);
        atomicAdd(&deg[v.w], 1);
    } else {
        for (int j = i; j < E; ++j) atomicAdd(&deg[dst[j]], 1);
    }
}

// ---------------------------------------------------------------------------
// Stage 1b: three-phase exclusive scan of deg[N] -> cursor[N]
// ---------------------------------------------------------------------------
__global__ __launch_bounds__(256) void scan_partial_kernel(
    const int* __restrict__ deg, int* __restrict__ bsum, int N)
{
    const int t = threadIdx.x;
    const int base = (blockIdx.x * 256 + t) * 4;
    int s = 0;
    if (base + 4 <= N) {
        const int4 v = *(const int4*)(deg + base);
        s = v.x + v.y + v.z + v.w;
    } else {
        for (int j = base; j < N; ++j) s += deg[j];
    }
    __shared__ int red[256];
    red[t] = s;
    __syncthreads();
    for (int off = 128; off; off >>= 1) {
        if (t < off) red[t] += red[t + off];
        __syncthreads();
    }
    if (t == 0) bsum[blockIdx.x] = red[0];
}

__global__ __launch_bounds__(64) void scan_top_kernel(
    const int* __restrict__ bsum, int* __restrict__ boffs, int nb)
{
    __shared__ int sh[64];
    const int t = threadIdx.x;
    const int v = (t < nb) ? bsum[t] : 0;
    sh[t] = v;
    __syncthreads();
    for (int off = 1; off < 64; off <<= 1) {
        const int u = (t >= off) ? sh[t - off] : 0;
        __syncthreads();
        sh[t] += u;
        __syncthreads();
    }
    if (t < nb) boffs[t] = sh[t] - v;      // exclusive
}

__global__ __launch_bounds__(256) void scan_final_kernel(
    const int* __restrict__ deg, const int* __restrict__ boffs,
    int* __restrict__ cursor, int N)
{
    const int t = threadIdx.x;
    const int base = (blockIdx.x * 256 + t) * 4;
    int v0 = 0, v1 = 0, v2 = 0, v3 = 0;
    if (base + 4 <= N) {
        const int4 v = *(const int4*)(deg + base);
        v0 = v.x; v1 = v.y; v2 = v.z; v3 = v.w;
    } else {
        if (base     < N) v0 = deg[base];
        if (base + 1 < N) v1 = deg[base + 1];
        if (base + 2 < N) v2 = deg[base + 2];
        if (base + 3 < N) v3 = deg[base + 3];
    }
    const int s = v0 + v1 + v2 + v3;
    __shared__ int sh[256];
    sh[t] = s;
    __syncthreads();
    for (int off = 1; off < 256; off <<= 1) {
        const int u = (t >= off) ? sh[t - off] : 0;
        __syncthreads();
        sh[t] += u;
        __syncthreads();
    }
    int ex = boffs[blockIdx.x] + sh[t] - s;
    if (base < N)     { cursor[base]     = ex; } ex += v0;
    if (base + 1 < N) { cursor[base + 1] = ex; } ex += v1;
    if (base + 2 < N) { cursor[base + 2] = ex; } ex += v2;
    if (base + 3 < N) { cursor[base + 3] = ex; }
}

// ---------------------------------------------------------------------------
// Stage 1c: scatter (src, dst, eid) as one int4 into dst-grouped order
// ---------------------------------------------------------------------------
__global__ __launch_bounds__(256) void scatter_kernel(
    const int* __restrict__ src, const int* __restrict__ dst,
    int* __restrict__ cursor, int4* __restrict__ sde, int E)
{
    const int i = blockIdx.x * 256 + threadIdx.x;
    if (i < E) {
        const int sv = src[i];
        const int dv = dst[i];
        const int p = atomicAdd(&cursor[dv], 1);
        sde[p] = make_int4(sv, dv, i, 0);
    }
}

// ---------------------------------------------------------------------------
// Stage 1d: EDGE-PARALLEL gather-reduce, scalar-uniform metadata/ea path.
// One wave per CH consecutive dst-sorted edges. All metadata + ea rows are
// wave-uniform -> scalar loads (SGPRs), FMAs take SGPR operands. Interior
// segments flushed with plain stores; chunk-boundary nodes with atomicAdd.
// Requires agg pre-zeroed.
// ---------------------------------------------------------------------------
__device__ __forceinline__ void flush_row(
    float* __restrict__ agg, int node, int d, float2 acc, int first, int last)
{
    float* p = agg + (size_t)node * D + d;
    if (node == first || node == last) {
        if (acc.x != 0.f) atomicAdd(p,     acc.x);
        if (acc.y != 0.f) atomicAdd(p + 1, acc.y);
    } else {
        *(float2*)p = acc;
    }
}

__global__ __launch_bounds__(256) void gine_reduce_kernel(
    const float* __restrict__ x, const int4* __restrict__ sde,
    const float* __restrict__ ea, const float* __restrict__ We,
    const float* __restrict__ be, float* __restrict__ agg, int E)
{
    const int wave = threadIdx.x >> 6;
    const int lane = threadIdx.x & 63;
    const int chunk = __builtin_amdgcn_readfirstlane(blockIdx.x * 4 + wave);
    const int e0 = chunk * CH;
    if (e0 >= E) return;
    const int kmax = min(CH, E - e0);
    const int d = lane * 2;

    // this lane's two columns of We + bias in registers
    float2 w[16];
    #pragma unroll
    for (int j = 0; j < 16; ++j) w[j] = *(const float2*)(We + j * D + d);
    const float2 bb = *(const float2*)(be + d);

    const int first = sde[e0].y;              // scalar load
    const int last  = sde[e0 + kmax - 1].y;   // scalar load

    float2 acc = make_float2(0.f, 0.f);
    int cur = first;

    for (int k0 = 0; k0 < kmax; k0 += 4) {
        const int kn = min(4, kmax - k0);

        // wave-uniform metadata for 4 edges (scalar loads)
        int4 m[4];
        #pragma unroll
        for (int j = 0; j < 4; ++j) {
            const int kk = k0 + (j < kn ? j : kn - 1);
            m[j] = sde[e0 + kk];
        }

        // per-lane x gathers for all 4 edges (independent, issued up front)
        float2 xv[4];
        #pragma unroll
        for (int j = 0; j < 4; ++j)
            xv[j] = *(const float2*)(x + (size_t)m[j].x * D + d);

        // wave-uniform ea rows (scalar 64B loads)
        float4 A[4][4];
        #pragma unroll
        for (int j = 0; j < 4; ++j) {
            const float4* p = (const float4*)(ea + (size_t)m[j].z * 16);
            A[j][0] = p[0]; A[j][1] = p[1]; A[j][2] = p[2]; A[j][3] = p[3];
        }

        #pragma unroll
        for (int j = 0; j < 4; ++j) {
            if (j < kn) {
                const int dk = m[j].y;
                if (dk != cur) {            // scalar compare/branch
                    flush_row(agg, cur, d, acc, first, last);
                    acc = make_float2(0.f, 0.f);
                    cur = dk;
                }
                float m0 = bb.x + xv[j].x;
                float m1 = bb.y + xv[j].y;
                const float av[16] = {
                    A[j][0].x, A[j][0].y, A[j][0].z, A[j][0].w,
                    A[j][1].x, A[j][1].y, A[j][1].z, A[j][1].w,
                    A[j][2].x, A[j][2].y, A[j][2].z, A[j][2].w,
                    A[j][3].x, A[j][3].y, A[j][3].z, A[j][3].w};
                #pragma unroll
                for (int jj = 0; jj < 16; ++jj) {
                    m0 += av[jj] * w[jj].x;
                    m1 += av[jj] * w[jj].y;
                }
                acc.x += m0 > 0.f ? m0 : 0.f;
                acc.y += m1 > 0.f ? m1 : 0.f;
            }
        }
    }
    flush_row(agg, cur, d, acc, first, last);
}

// ---------------------------------------------------------------------------
// Stage 2: fused 2-layer MLP on h = (1+eps)*x + agg
// 48-row tile, 192 threads, thread = 4 rows x 8 cols; LDS stride 132.
// ---------------------------------------------------------------------------
#define MT_ROWS 48
#define SH_STR  132
__global__ __launch_bounds__(192) void mlp_kernel(
    const float* __restrict__ x, const float* __restrict__ agg,
    const float* __restrict__ epsp,
    const float* __restrict__ W1, const float* __restrict__ b1,
    const float* __restrict__ W2, const float* __restrict__ b2,
    float* __restrict__ xres, int N)
{
    __shared__ float sh[MT_ROWS * SH_STR];
    __shared__ float st[MT_ROWS * SH_STR];
    const int row0 = blockIdx.x * MT_ROWS;
    const float ep = 1.0f + epsp[0];

    for (int i = threadIdx.x; i < MT_ROWS * D / 4; i += 192) {
        const int flat = i * 4;
        const int r = flat >> 7;
        const int c = flat & (D - 1);
        const int row = row0 + r;
        float4 hv;
        if (row < N) {
            const float4 xv = *(const float4*)(x   + (size_t)row * D + c);
            const float4 av = *(const float4*)(agg + (size_t)row * D + c);
            hv = make_float4(ep * xv.x + av.x, ep * xv.y + av.y,
                             ep * xv.z + av.z, ep * xv.w + av.w);
        } else {
            hv = make_float4(0.f, 0.f, 0.f, 0.f);
        }
        *(float4*)(sh + r * SH_STR + c) = hv;
    }
    __syncthreads();

    const int cg = (threadIdx.x & 15) * 8;   // 8 output cols
    const int rg = (threadIdx.x >> 4) * 4;   // 4 rows

    float acc[4][8];

    // ---- layer 1: t = relu(h @ W1 + b1) ----
    {
        const float4 bA = *(const float4*)(b1 + cg);
        const float4 bB = *(const float4*)(b1 + cg + 4);
        #pragma unroll
        for (int r = 0; r < 4; ++r) {
            acc[r][0] = bA.x; acc[r][1] = bA.y; acc[r][2] = bA.z; acc[r][3] = bA.w;
            acc[r][4] = bB.x; acc[r][5] = bB.y; acc[r][6] = bB.z; acc[r][7] = bB.w;
        }
        for (int k = 0; k < D; k += 4) {
            float wv[4][8];
            #pragma unroll
            for (int kk = 0; kk < 4; ++kk) {
                const float4 wa = *(const float4*)(W1 + (size_t)(k + kk) * D + cg);
                const float4 wb = *(const float4*)(W1 + (size_t)(k + kk) * D + cg + 4);
                wv[kk][0] = wa.x; wv[kk][1] = wa.y; wv[kk][2] = wa.z; wv[kk][3] = wa.w;
                wv[kk][4] = wb.x; wv[kk][5] = wb.y; wv[kk][6] = wb.z; wv[kk][7] = wb.w;
            }
            #pragma unroll
            for (int r = 0; r < 4; ++r) {
                const float4 h4 = *(const float4*)(sh + (rg + r) * SH_STR + k);
                const float hk[4] = {h4.x, h4.y, h4.z, h4.w};
                #pragma unroll
                for (int kk = 0; kk < 4; ++kk)
                    #pragma unroll
                    for (int c = 0; c < 8; ++c)
                        acc[r][c] += hk[kk] * wv[kk][c];
            }
        }
        #pragma unroll
        for (int r = 0; r < 4; ++r) {
            float4 oa, ob;
            oa.x = acc[r][0] > 0.f ? acc[r][0] : 0.f;
            oa.y = acc[r][1] > 0.f ? acc[r][1] : 0.f;
            oa.z = acc[r][2] > 0.f ? acc[r][2] : 0.f;
            oa.w = acc[r][3] > 0.f ? acc[r][3] : 0.f;
            ob.x = acc[r][4] > 0.f ? acc[r][4] : 0.f;
            ob.y = acc[r][5] > 0.f ? acc[r][5] : 0.f;
            ob.z = acc[r][6] > 0.f ? acc[r][6] : 0.f;
            ob.w = acc[r][7] > 0.f ? acc[r][7] : 0.f;
            *(float4*)(st + (rg + r) * SH_STR + cg)     = oa;
            *(float4*)(st + (rg + r) * SH_STR + cg + 4) = ob;
        }
    }
    __syncthreads();

    // ---- layer 2: x_res = t @ W2 + b2 ----
    {
        const float4 bA = *(const float4*)(b2 + cg);
        const float4 bB = *(const float4*)(b2 + cg + 4);
        #pragma unroll
        for (int r = 0; r < 4; ++r) {
            acc[r][0] = bA.x; acc[r][1] = bA.y; acc[r][2] = bA.z; acc[r][3] = bA.w;
            acc[r][4] = bB.x; acc[r][5] = bB.y; acc[r][6] = bB.z; acc[r][7] = bB.w;
        }
        for (int k = 0; k < D; k += 4) {
            float wv[4][8];
            #pragma unroll
            for (int kk = 0; kk < 4; ++kk) {
                const float4 wa = *(const float4*)(W2 + (size_t)(k + kk) * D + cg);
                const float4 wb = *(const float4*)(W2 + (size_t)(k + kk) * D + cg + 4);
                wv[kk][0] = wa.x; wv[kk][1] = wa.y; wv[kk][2] = wa.z; wv[kk][3] = wa.w;
                wv[kk][4] = wb.x; wv[kk][5] = wb.y; wv[kk][6] = wb.z; wv[kk][7] = wb.w;
            }
            #pragma unroll
            for (int r = 0; r < 4; ++r) {
                const float4 h4 = *(const float4*)(st + (rg + r) * SH_STR + k);
                const float hk[4] = {h4.x, h4.y, h4.z, h4.w};
                #pragma unroll
                for (int kk = 0; kk < 4; ++kk)
                    #pragma unroll
                    for (int c = 0; c < 8; ++c)
                        acc[r][c] += hk[kk] * wv[kk][c];
            }
        }
        #pragma unroll
        for (int r = 0; r < 4; ++r) {
            const int row = row0 + rg + r;
            if (row < N) {
                *(float4*)(xres + (size_t)row * D + cg) =
                    make_float4(acc[r][0], acc[r][1], acc[r][2], acc[r][3]);
                *(float4*)(xres + (size_t)row * D + cg + 4) =
                    make_float4(acc[r][4], acc[r][5], acc[r][6], acc[r][7]);
            }
        }
    }
}

// ---------------------------------------------------------------------------
// Stage 3: per-(graph,pocket) masked sums
// ---------------------------------------------------------------------------
#define PPARTS 32
__global__ __launch_bounds__(128) void pocket_sum_kernel(
    const float* __restrict__ xres, const float* __restrict__ pmask,
    const int* __restrict__ batch,
    float* __restrict__ psum, float* __restrict__ pcnt, int N)
{
    const int g = blockIdx.x / PPARTS;
    const int part = blockIdx.x % PPARTS;

    int lo, hi;
    {
        int l = 0, r = N;
        while (l < r) { int m = (l + r) >> 1; if (batch[m] < g) l = m + 1; else r = m; }
        lo = l;
        r = N;
        while (l < r) { int m = (l + r) >> 1; if (batch[m] < g + 1) l = m + 1; else r = m; }
        hi = l;
    }
    const int cnt = hi - lo;
    const int per = (cnt + PPARTS - 1) / PPARTS;
    const int s = lo + part * per;
    const int e = min(s + per, hi);

    const int d = threadIdx.x;
    float acc[K];
    #pragma unroll
    for (int k = 0; k < K; ++k) acc[k] = 0.0f;
    float c = 0.0f;

    for (int n = s; n < e; ++n) {
        const float xv = xres[(size_t)n * D + d];
        const float4 m0 = *(const float4*)(pmask + (size_t)n * K);
        const float4 m1 = *(const float4*)(pmask + (size_t)n * K + 4);
        acc[0] += m0.x * xv; acc[1] += m0.y * xv;
        acc[2] += m0.z * xv; acc[3] += m0.w * xv;
        acc[4] += m1.x * xv; acc[5] += m1.y * xv;
        acc[6] += m1.z * xv; acc[7] += m1.w * xv;
        if (d < K) c += pmask[(size_t)n * K + d];
    }
    #pragma unroll
    for (int k = 0; k < K; ++k)
        atomicAdd(&psum[(size_t)g * (K * D) + k * D + d], acc[k]);
    if (d < K) atomicAdd(&pcnt[g * K + d], c);
}

// ---------------------------------------------------------------------------
// Stage 4: pocket_emb = (psum / (pcnt + 1e-9)) @ Wv + bv
// ---------------------------------------------------------------------------
__global__ __launch_bounds__(128) void pocket_emb_kernel(
    const float* __restrict__ psum, const float* __restrict__ pcnt,
    const float* __restrict__ Wv, const float* __restrict__ bv,
    float* __restrict__ pemb)
{
    __shared__ float smean[K * D];
    __shared__ float scnt[K];
    const int g = blockIdx.x;
    const int d = threadIdx.x;
    if (d < K) scnt[d] = pcnt[g * K + d];
    __syncthreads();
    #pragma unroll
    for (int k = 0; k < K; ++k)
        smean[k * D + d] = psum[(size_t)g * (K * D) + k * D + d] / (scnt[k] + 1e-9f);
    __syncthreads();

    float acc[K];
    const float bvv = bv[d];
    #pragma unroll
    for (int k = 0; k < K; ++k) acc[k] = bvv;
    for (int j = 0; j < D; ++j) {
        const float w = Wv[j * D + d];
        #pragma unroll
        for (int k = 0; k < K; ++k) acc[k] += smean[k * D + j] * w;
    }
    #pragma unroll
    for (int k = 0; k < K; ++k)
        pemb[(size_t)g * (K * D) + k * D + d] = acc[k];
}

// ---------------------------------------------------------------------------
// Stage 5: feedback gather + LayerNorm + ReLU. One wave per node.
// ---------------------------------------------------------------------------
__global__ __launch_bounds__(256) void ln_kernel(
    const float* __restrict__ xres, const float* __restrict__ pmask,
    const int* __restrict__ batch, const float* __restrict__ pemb,
    const float* __restrict__ gamma, const float* __restrict__ beta,
    float* __restrict__ out, int N)
{
    const int wave = threadIdx.x >> 6;
    const int lane = threadIdx.x & 63;
    const int n = blockIdx.x * 4 + wave;
    if (n >= N) return;
    const int d = lane * 2;

    float2 v = *(const float2*)(xres + (size_t)n * D + d);
    const int g = batch[n];
    const float* pe = pemb + (size_t)g * (K * D);
    const float4 m0 = *(const float4*)(pmask + (size_t)n * K);
    const float4 m1 = *(const float4*)(pmask + (size_t)n * K + 4);
    const float mk[K] = {m0.x, m0.y, m0.z, m0.w, m1.x, m1.y, m1.z, m1.w};
    #pragma unroll
    for (int k = 0; k < K; ++k) {
        if (mk[k] != 0.0f) {   // wave-uniform branch
            const float2 p = *(const float2*)(pe + k * D + d);
            v.x += mk[k] * p.x;
            v.y += mk[k] * p.y;
        }
    }

    float s = v.x + v.y;
    #pragma unroll
    for (int off = 32; off; off >>= 1) s += __shfl_xor(s, off, 64);
    const float mu = s * (1.0f / 128.0f);
    const float d0 = v.x - mu, d1 = v.y - mu;
    float sq = d0 * d0 + d1 * d1;
    #pragma unroll
    for (int off = 32; off; off >>= 1) sq += __shfl_xor(sq, off, 64);
    const float var = sq * (1.0f / 128.0f);
    const float inv = rsqrtf(var + 1e-5f);

    const float2 gm = *(const float2*)(gamma + d);
    const float2 bt = *(const float2*)(beta + d);
    float y0 = d0 * inv * gm.x + bt.x;
    float y1 = d1 * inv * gm.y + bt.y;
    y0 = y0 > 0.0f ? y0 : 0.0f;
    y1 = y1 > 0.0f ? y1 : 0.0f;
    *(float2*)(out + (size_t)n * D + d) = make_float2(y0, y1);
}

// ---------------------------------------------------------------------------
extern "C" void kernel_launch(void* const* d_in, const int* in_sizes, int n_in,
                              void* d_out, int out_size, void* d_ws, size_t ws_size,
                              hipStream_t stream)
{
    const float* x     = (const float*)d_in[0];
    const int*   ei    = (const int*)  d_in[1];
    const float* ea    = (const float*)d_in[2];
    const float* pmask = (const float*)d_in[3];
    const int*   batch = (const int*)  d_in[4];
    const float* We    = (const float*)d_in[5];
    const float* be    = (const float*)d_in[6];
    const float* W1    = (const float*)d_in[7];
    const float* b1    = (const float*)d_in[8];
    const float* W2    = (const float*)d_in[9];
    const float* b2    = (const float*)d_in[10];
    const float* epsp  = (const float*)d_in[11];
    const float* gamma = (const float*)d_in[12];
    const float* beta  = (const float*)d_in[13];
    const float* Wv    = (const float*)d_in[14];
    const float* bv    = (const float*)d_in[15];
    float* out = (float*)d_out;

    const int N = in_sizes[0] / D;     // 50000
    const int E = in_sizes[1] / 2;     // 600000
    const int* src = ei;
    const int* dst = ei + E;

    // Workspace layout: [deg | agg | psum | pcnt] contiguous (single memset),
    // then xres (CSR scratch aliased inside), pemb, scan scratch.
    int*   deg  = (int*)d_ws;                           // N
    float* agg  = (float*)(deg + N);                    // N*D
    float* psum = agg + (size_t)N * D;                  // B*K*D
    float* pcnt = psum + (size_t)BGRAPH * K * D;        // B*K
    float* xres = pcnt + (size_t)BGRAPH * K;            // N*D
    float* pemb = xres + (size_t)N * D;                 // B*K*D
    float* extra = pemb + (size_t)BGRAPH * K * D;       // scan scratch

    // CSR scratch aliased onto xres (consumed before mlp writes xres)
    int*  cursor = (int*)xres;                          // N
    int4* sde    = (int4*)(((uintptr_t)(cursor + N) + 15) & ~(uintptr_t)15); // E
    int*  bsum   = (int*)extra;                         // 64
    int*  boffs  = bsum + 64;                           // 64

    const int nb = (N + 1023) / 1024;                   // scan blocks (49)
    const int nchunks = (E + CH - 1) / CH;              // 9375

    const size_t zero_bytes =
        ((size_t)N + (size_t)N * D + (size_t)BGRAPH * K * D + BGRAPH * K) * sizeof(float);
    hipMemsetAsync(d_ws, 0, zero_bytes, stream);

    hist_kernel<<<(E / 4 + 255) / 256, 256, 0, stream>>>(dst, deg, E);
    scan_partial_kernel<<<nb, 256, 0, stream>>>(deg, bsum, N);
    scan_top_kernel<<<1, 64, 0, stream>>>(bsum, boffs, nb);
    scan_final_kernel<<<nb, 256, 0, stream>>>(deg, boffs, cursor, N);
    scatter_kernel<<<(E + 255) / 256, 256, 0, stream>>>(src, dst, cursor, sde, E);
    gine_reduce_kernel<<<(nchunks + 3) / 4, 256, 0, stream>>>(
        x, sde, ea, We, be, agg, E);

    mlp_kernel<<<(N + MT_ROWS - 1) / MT_ROWS, 192, 0, stream>>>(
        x, agg, epsp, W1, b1, W2, b2, xres, N);
    pocket_sum_kernel<<<BGRAPH * PPARTS, 128, 0, stream>>>(
        xres, pmask, batch, psum, pcnt, N);
    pocket_emb_kernel<<<BGRAPH, 128, 0, stream>>>(psum, pcnt, Wv, bv, pemb);
    ln_kernel<<<(N + 3) / 4, 256, 0, stream>>>(
        xres, pmask, batch, pemb, gamma, beta, out, N);
}

// Round 6
// 405.556 us; speedup vs baseline: 1.5013x; 1.0089x over previous
//
#include <hip/hip_runtime.h>
#include <hip/hip_bf16.h>
#include <stdint.h>

#define D 128
#define K 8
#define BGRAPH 64
#define CH 64    // edges per wave in gine_reduce
#define GRP 4    // edges per inner group

// ---------------------------------------------------------------------------
// Stage 0: cast x to bf16 for the gather path (halves gather traffic)
// ---------------------------------------------------------------------------
__global__ __launch_bounds__(256) void cast_x_kernel(
    const float* __restrict__ x, __hip_bfloat16* __restrict__ xb, int n)
{
    const int i = (blockIdx.x * 256 + threadIdx.x) * 8;
    if (i + 8 > n) return;
    const float4 a = *(const float4*)(x + i);
    const float4 b = *(const float4*)(x + i + 4);
    __hip_bfloat16 v[8];
    v[0] = __float2bfloat16(a.x); v[1] = __float2bfloat16(a.y);
    v[2] = __float2bfloat16(a.z); v[3] = __float2bfloat16(a.w);
    v[4] = __float2bfloat16(b.x); v[5] = __float2bfloat16(b.y);
    v[6] = __float2bfloat16(b.z); v[7] = __float2bfloat16(b.w);
    *(uint4*)(xb + i) = *(const uint4*)v;
}

// ---------------------------------------------------------------------------
// Stage 1a: in-degree histogram over dst (4 edges/thread, int4 loads)
// ---------------------------------------------------------------------------
__global__ __launch_bounds__(256) void hist_kernel(
    const int* __restrict__ dst, int* __restrict__ deg, int E)
{
    const int i = (blockIdx.x * 256 + threadIdx.x) * 4;
    if (i + 4 <= E) {
        const int4 v = *(const int4*)(dst + i);
        atomicAdd(&deg[v.x], 1);
        atomicAdd(&deg[v.y], 1);
        atomicAdd(&deg[v.z], 1);
        atomicAdd(&deg[v.w], 1);
    } else {
        for (int j = i; j < E; ++j) atomicAdd(&deg[dst[j]], 1);
    }
}

// ---------------------------------------------------------------------------
// Stage 1b: three-phase exclusive scan of deg[N] -> cursor[N]
// ---------------------------------------------------------------------------
__global__ __launch_bounds__(256) void scan_partial_kernel(
    const int* __restrict__ deg, int* __restrict__ bsum, int N)
{
    const int t = threadIdx.x;
    const int base = (blockIdx.x * 256 + t) * 4;
    int s = 0;
    if (base + 4 <= N) {
        const int4 v = *(const int4*)(deg + base);
        s = v.x + v.y + v.z + v.w;
    } else {
        for (int j = base; j < N; ++j) s += deg[j];
    }
    __shared__ int red[256];
    red[t] = s;
    __syncthreads();
    for (int off = 128; off; off >>= 1) {
        if (t < off) red[t] += red[t + off];
        __syncthreads();
    }
    if (t == 0) bsum[blockIdx.x] = red[0];
}

__global__ __launch_bounds__(64) void scan_top_kernel(
    const int* __restrict__ bsum, int* __restrict__ boffs, int nb)
{
    __shared__ int sh[64];
    const int t = threadIdx.x;
    const int v = (t < nb) ? bsum[t] : 0;
    sh[t] = v;
    __syncthreads();
    for (int off = 1; off < 64; off <<= 1) {
        const int u = (t >= off) ? sh[t - off] : 0;
        __syncthreads();
        sh[t] += u;
        __syncthreads();
    }
    if (t < nb) boffs[t] = sh[t] - v;      // exclusive
}

__global__ __launch_bounds__(256) void scan_final_kernel(
    const int* __restrict__ deg, const int* __restrict__ boffs,
    int* __restrict__ cursor, int N)
{
    const int t = threadIdx.x;
    const int base = (blockIdx.x * 256 + t) * 4;
    int v0 = 0, v1 = 0, v2 = 0, v3 = 0;
    if (base + 4 <= N) {
        const int4 v = *(const int4*)(deg + base);
        v0 = v.x; v1 = v.y; v2 = v.z; v3 = v.w;
    } else {
        if (base     < N) v0 = deg[base];
        if (base + 1 < N) v1 = deg[base + 1];
        if (base + 2 < N) v2 = deg[base + 2];
        if (base + 3 < N) v3 = deg[base + 3];
    }
    const int s = v0 + v1 + v2 + v3;
    __shared__ int sh[256];
    sh[t] = s;
    __syncthreads();
    for (int off = 1; off < 256; off <<= 1) {
        const int u = (t >= off) ? sh[t - off] : 0;
        __syncthreads();
        sh[t] += u;
        __syncthreads();
    }
    int ex = boffs[blockIdx.x] + sh[t] - s;
    if (base < N)     { cursor[base]     = ex; } ex += v0;
    if (base + 1 < N) { cursor[base + 1] = ex; } ex += v1;
    if (base + 2 < N) { cursor[base + 2] = ex; } ex += v2;
    if (base + 3 < N) { cursor[base + 3] = ex; }
}

// ---------------------------------------------------------------------------
// Stage 1c: scatter (src, dst, eid) as one int4 into dst-grouped order
// ---------------------------------------------------------------------------
__global__ __launch_bounds__(256) void scatter_kernel(
    const int* __restrict__ src, const int* __restrict__ dst,
    int* __restrict__ cursor, int4* __restrict__ sde, int E)
{
    const int i = blockIdx.x * 256 + threadIdx.x;
    if (i < E) {
        const int sv = src[i];
        const int dv = dst[i];
        const int p = atomicAdd(&cursor[dv], 1);
        sde[p] = make_int4(sv, dv, i, 0);
    }
}

// ---------------------------------------------------------------------------
// Stage 1d: edge-parallel gather-reduce; scalar metadata/ea, bf16 x gathers,
// meta prefetched 2 groups ahead, x 1 group ahead.
// ---------------------------------------------------------------------------
__device__ __forceinline__ void flush_row(
    float* __restrict__ agg, int node, int d, float2 acc, int first, int last)
{
    float* p = agg + (size_t)node * D + d;
    if (node == first || node == last) {
        if (acc.x != 0.f) atomicAdd(p,     acc.x);
        if (acc.y != 0.f) atomicAdd(p + 1, acc.y);
    } else {
        *(float2*)p = acc;
    }
}

__global__ __launch_bounds__(256) void gine_reduce_kernel(
    const __hip_bfloat16* __restrict__ xb, const int4* __restrict__ sde,
    const float* __restrict__ ea, const float* __restrict__ We,
    const float* __restrict__ be, float* __restrict__ agg, int E)
{
    const int wave = threadIdx.x >> 6;
    const int lane = threadIdx.x & 63;
    const int chunk = __builtin_amdgcn_readfirstlane(blockIdx.x * 4 + wave);
    const int e0 = chunk * CH;
    if (e0 >= E) return;
    const int d = lane * 2;
    const int NG = CH / GRP;                  // 16 (E is a multiple of CH)

    // this lane's two columns of We + bias in registers
    float2 w[16];
    #pragma unroll
    for (int j = 0; j < 16; ++j) w[j] = *(const float2*)(We + j * D + d);
    const float2 bb = *(const float2*)(be + d);

    // prologue: meta for groups 0 and 1; x for group 0
    int4 mcur[GRP], mnext[GRP];
    #pragma unroll
    for (int j = 0; j < GRP; ++j) mcur[j] = sde[e0 + j];
    #pragma unroll
    for (int j = 0; j < GRP; ++j) mnext[j] = sde[e0 + GRP + j];
    __hip_bfloat162 xcur[GRP];
    #pragma unroll
    for (int j = 0; j < GRP; ++j)
        xcur[j] = *(const __hip_bfloat162*)(xb + (size_t)mcur[j].x * D + d);

    const int first = mcur[0].y;
    const int last  = sde[e0 + CH - 1].y;

    float2 acc = make_float2(0.f, 0.f);
    int cur = first;

    for (int g = 0; g < NG; ++g) {
        // prefetch meta for g+2 and x for g+1 (mnext loaded last iteration)
        int4 mnn[GRP] = {};
        __hip_bfloat162 xn[GRP] = {};
        if (g + 2 < NG) {
            #pragma unroll
            for (int j = 0; j < GRP; ++j) mnn[j] = sde[e0 + (g + 2) * GRP + j];
        }
        if (g + 1 < NG) {
            #pragma unroll
            for (int j = 0; j < GRP; ++j)
                xn[j] = *(const __hip_bfloat162*)(xb + (size_t)mnext[j].x * D + d);
        }

        // ea rows for current group (wave-uniform scalar 64B loads)
        float4 A[GRP][4];
        #pragma unroll
        for (int j = 0; j < GRP; ++j) {
            const float4* p = (const float4*)(ea + (size_t)mcur[j].z * 16);
            A[j][0] = p[0]; A[j][1] = p[1]; A[j][2] = p[2]; A[j][3] = p[3];
        }

        #pragma unroll
        for (int j = 0; j < GRP; ++j) {
            const int dk = mcur[j].y;
            if (dk != cur) {                  // scalar compare/branch
                flush_row(agg, cur, d, acc, first, last);
                acc = make_float2(0.f, 0.f);
                cur = dk;
            }
            float m0 = bb.x + __bfloat162float(xcur[j].x);
            float m1 = bb.y + __bfloat162float(xcur[j].y);
            const float av[16] = {
                A[j][0].x, A[j][0].y, A[j][0].z, A[j][0].w,
                A[j][1].x, A[j][1].y, A[j][1].z, A[j][1].w,
                A[j][2].x, A[j][2].y, A[j][2].z, A[j][2].w,
                A[j][3].x, A[j][3].y, A[j][3].z, A[j][3].w};
            #pragma unroll
            for (int jj = 0; jj < 16; ++jj) {
                m0 += av[jj] * w[jj].x;
                m1 += av[jj] * w[jj].y;
            }
            acc.x += m0 > 0.f ? m0 : 0.f;
            acc.y += m1 > 0.f ? m1 : 0.f;
        }

        #pragma unroll
        for (int j = 0; j < GRP; ++j) {
            mcur[j] = mnext[j]; mnext[j] = mnn[j]; xcur[j] = xn[j];
        }
    }
    flush_row(agg, cur, d, acc, first, last);
}

// ---------------------------------------------------------------------------
// Stage 2: fused 2-layer MLP on h = (1+eps)*x + agg
// 64-row tile, 256 threads, thread = 4 rows x 8 cols; SINGLE LDS buffer
// (h tile overwritten by t tile after a barrier) -> 33.8 KB, 4 blocks/CU.
// ---------------------------------------------------------------------------
#define MT_ROWS 64
#define SH_STR  132
__global__ __launch_bounds__(256) void mlp_kernel(
    const float* __restrict__ x, const float* __restrict__ agg,
    const float* __restrict__ epsp,
    const float* __restrict__ W1, const float* __restrict__ b1,
    const float* __restrict__ W2, const float* __restrict__ b2,
    float* __restrict__ xres, int N)
{
    __shared__ float sh[MT_ROWS * SH_STR];
    const int row0 = blockIdx.x * MT_ROWS;
    const float ep = 1.0f + epsp[0];

    for (int i = threadIdx.x; i < MT_ROWS * D / 4; i += 256) {
        const int flat = i * 4;
        const int r = flat >> 7;
        const int c = flat & (D - 1);
        const int row = row0 + r;
        float4 hv;
        if (row < N) {
            const float4 xv = *(const float4*)(x   + (size_t)row * D + c);
            const float4 av = *(const float4*)(agg + (size_t)row * D + c);
            hv = make_float4(ep * xv.x + av.x, ep * xv.y + av.y,
                             ep * xv.z + av.z, ep * xv.w + av.w);
        } else {
            hv = make_float4(0.f, 0.f, 0.f, 0.f);
        }
        *(float4*)(sh + r * SH_STR + c) = hv;
    }
    __syncthreads();

    const int cg = (threadIdx.x & 15) * 8;   // 8 output cols
    const int rg = (threadIdx.x >> 4) * 4;   // 4 rows

    float acc[4][8];

    // ---- layer 1: t = relu(h @ W1 + b1), t kept in acc ----
    {
        const float4 bA = *(const float4*)(b1 + cg);
        const float4 bB = *(const float4*)(b1 + cg + 4);
        #pragma unroll
        for (int r = 0; r < 4; ++r) {
            acc[r][0] = bA.x; acc[r][1] = bA.y; acc[r][2] = bA.z; acc[r][3] = bA.w;
            acc[r][4] = bB.x; acc[r][5] = bB.y; acc[r][6] = bB.z; acc[r][7] = bB.w;
        }
        for (int k = 0; k < D; k += 4) {
            float wv[4][8];
            #pragma unroll
            for (int kk = 0; kk < 4; ++kk) {
                const float4 wa = *(const float4*)(W1 + (size_t)(k + kk) * D + cg);
                const float4 wb = *(const float4*)(W1 + (size_t)(k + kk) * D + cg + 4);
                wv[kk][0] = wa.x; wv[kk][1] = wa.y; wv[kk][2] = wa.z; wv[kk][3] = wa.w;
                wv[kk][4] = wb.x; wv[kk][5] = wb.y; wv[kk][6] = wb.z; wv[kk][7] = wb.w;
            }
            #pragma unroll
            for (int r = 0; r < 4; ++r) {
                const float4 h4 = *(const float4*)(sh + (rg + r) * SH_STR + k);
                const float hk[4] = {h4.x, h4.y, h4.z, h4.w};
                #pragma unroll
                for (int kk = 0; kk < 4; ++kk)
                    #pragma unroll
                    for (int c = 0; c < 8; ++c)
                        acc[r][c] += hk[kk] * wv[kk][c];
            }
        }
    }
    __syncthreads();   // all h reads done -> safe to overwrite sh with t

    #pragma unroll
    for (int r = 0; r < 4; ++r) {
        float4 oa, ob;
        oa.x = acc[r][0] > 0.f ? acc[r][0] : 0.f;
        oa.y = acc[r][1] > 0.f ? acc[r][1] : 0.f;
        oa.z = acc[r][2] > 0.f ? acc[r][2] : 0.f;
        oa.w = acc[r][3] > 0.f ? acc[r][3] : 0.f;
        ob.x = acc[r][4] > 0.f ? acc[r][4] : 0.f;
        ob.y = acc[r][5] > 0.f ? acc[r][5] : 0.f;
        ob.z = acc[r][6] > 0.f ? acc[r][6] : 0.f;
        ob.w = acc[r][7] > 0.f ? acc[r][7] : 0.f;
        *(float4*)(sh + (rg + r) * SH_STR + cg)     = oa;
        *(float4*)(sh + (rg + r) * SH_STR + cg + 4) = ob;
    }
    __syncthreads();

    // ---- layer 2: x_res = t @ W2 + b2 ----
    {
        const float4 bA = *(const float4*)(b2 + cg);
        const float4 bB = *(const float4*)(b2 + cg + 4);
        #pragma unroll
        for (int r = 0; r < 4; ++r) {
            acc[r][0] = bA.x; acc[r][1] = bA.y; acc[r][2] = bA.z; acc[r][3] = bA.w;
            acc[r][4] = bB.x; acc[r][5] = bB.y; acc[r][6] = bB.z; acc[r][7] = bB.w;
        }
        for (int k = 0; k < D; k += 4) {
            float wv[4][8];
            #pragma unroll
            for (int kk = 0; kk < 4; ++kk) {
                const float4 wa = *(const float4*)(W2 + (size_t)(k + kk) * D + cg);
                const float4 wb = *(const float4*)(W2 + (size_t)(k + kk) * D + cg + 4);
                wv[kk][0] = wa.x; wv[kk][1] = wa.y; wv[kk][2] = wa.z; wv[kk][3] = wa.w;
                wv[kk][4] = wb.x; wv[kk][5] = wb.y; wv[kk][6] = wb.z; wv[kk][7] = wb.w;
            }
            #pragma unroll
            for (int r = 0; r < 4; ++r) {
                const float4 h4 = *(const float4*)(sh + (rg + r) * SH_STR + k);
                const float hk[4] = {h4.x, h4.y, h4.z, h4.w};
                #pragma unroll
                for (int kk = 0; kk < 4; ++kk)
                    #pragma unroll
                    for (int c = 0; c < 8; ++c)
                        acc[r][c] += hk[kk] * wv[kk][c];
            }
        }
        #pragma unroll
        for (int r = 0; r < 4; ++r) {
            const int row = row0 + rg + r;
            if (row < N) {
                *(float4*)(xres + (size_t)row * D + cg) =
                    make_float4(acc[r][0], acc[r][1], acc[r][2], acc[r][3]);
                *(float4*)(xres + (size_t)row * D + cg + 4) =
                    make_float4(acc[r][4], acc[r][5], acc[r][6], acc[r][7]);
            }
        }
    }
}

// ---------------------------------------------------------------------------
// Stage 3: per-(graph,pocket) masked sums
// ---------------------------------------------------------------------------
#define PPARTS 32
__global__ __launch_bounds__(128) void pocket_sum_kernel(
    const float* __restrict__ xres, const float* __restrict__ pmask,
    const int* __restrict__ batch,
    float* __restrict__ psum, float* __restrict__ pcnt, int N)
{
    const int g = blockIdx.x / PPARTS;
    const int part = blockIdx.x % PPARTS;

    int lo, hi;
    {
        int l = 0, r = N;
        while (l < r) { int m = (l + r) >> 1; if (batch[m] < g) l = m + 1; else r = m; }
        lo = l;
        r = N;
        while (l < r) { int m = (l + r) >> 1; if (batch[m] < g + 1) l = m + 1; else r = m; }
        hi = l;
    }
    const int cnt = hi - lo;
    const int per = (cnt + PPARTS - 1) / PPARTS;
    const int s = lo + part * per;
    const int e = min(s + per, hi);

    const int d = threadIdx.x;
    float acc[K];
    #pragma unroll
    for (int k = 0; k < K; ++k) acc[k] = 0.0f;
    float c = 0.0f;

    for (int n = s; n < e; ++n) {
        const float xv = xres[(size_t)n * D + d];
        const float4 m0 = *(const float4*)(pmask + (size_t)n * K);
        const float4 m1 = *(const float4*)(pmask + (size_t)n * K + 4);
        acc[0] += m0.x * xv; acc[1] += m0.y * xv;
        acc[2] += m0.z * xv; acc[3] += m0.w * xv;
        acc[4] += m1.x * xv; acc[5] += m1.y * xv;
        acc[6] += m1.z * xv; acc[7] += m1.w * xv;
        if (d < K) c += pmask[(size_t)n * K + d];
    }
    #pragma unroll
    for (int k = 0; k < K; ++k)
        atomicAdd(&psum[(size_t)g * (K * D) + k * D + d], acc[k]);
    if (d < K) atomicAdd(&pcnt[g * K + d], c);
}

// ---------------------------------------------------------------------------
// Stage 4: pocket_emb = (psum / (pcnt + 1e-9)) @ Wv + bv
// ---------------------------------------------------------------------------
__global__ __launch_bounds__(128) void pocket_emb_kernel(
    const float* __restrict__ psum, const float* __restrict__ pcnt,
    const float* __restrict__ Wv, const float* __restrict__ bv,
    float* __restrict__ pemb)
{
    __shared__ float smean[K * D];
    __shared__ float scnt[K];
    const int g = blockIdx.x;
    const int d = threadIdx.x;
    if (d < K) scnt[d] = pcnt[g * K + d];
    __syncthreads();
    #pragma unroll
    for (int k = 0; k < K; ++k)
        smean[k * D + d] = psum[(size_t)g * (K * D) + k * D + d] / (scnt[k] + 1e-9f);
    __syncthreads();

    float acc[K];
    const float bvv = bv[d];
    #pragma unroll
    for (int k = 0; k < K; ++k) acc[k] = bvv;
    for (int j = 0; j < D; ++j) {
        const float w = Wv[j * D + d];
        #pragma unroll
        for (int k = 0; k < K; ++k) acc[k] += smean[k * D + j] * w;
    }
    #pragma unroll
    for (int k = 0; k < K; ++k)
        pemb[(size_t)g * (K * D) + k * D + d] = acc[k];
}

// ---------------------------------------------------------------------------
// Stage 5: feedback gather + LayerNorm + ReLU. One wave per node.
// ---------------------------------------------------------------------------
__global__ __launch_bounds__(256) void ln_kernel(
    const float* __restrict__ xres, const float* __restrict__ pmask,
    const int* __restrict__ batch, const float* __restrict__ pemb,
    const float* __restrict__ gamma, const float* __restrict__ beta,
    float* __restrict__ out, int N)
{
    const int wave = threadIdx.x >> 6;
    const int lane = threadIdx.x & 63;
    const int n = blockIdx.x * 4 + wave;
    if (n >= N) return;
    const int d = lane * 2;

    float2 v = *(const float2*)(xres + (size_t)n * D + d);
    const int g = batch[n];
    const float* pe = pemb + (size_t)g * (K * D);
    const float4 m0 = *(const float4*)(pmask + (size_t)n * K);
    const float4 m1 = *(const float4*)(pmask + (size_t)n * K + 4);
    const float mk[K] = {m0.x, m0.y, m0.z, m0.w, m1.x, m1.y, m1.z, m1.w};
    #pragma unroll
    for (int k = 0; k < K; ++k) {
        if (mk[k] != 0.0f) {   // wave-uniform branch
            const float2 p = *(const float2*)(pe + k * D + d);
            v.x += mk[k] * p.x;
            v.y += mk[k] * p.y;
        }
    }

    float s = v.x + v.y;
    #pragma unroll
    for (int off = 32; off; off >>= 1) s += __shfl_xor(s, off, 64);
    const float mu = s * (1.0f / 128.0f);
    const float d0 = v.x - mu, d1 = v.y - mu;
    float sq = d0 * d0 + d1 * d1;
    #pragma unroll
    for (int off = 32; off; off >>= 1) sq += __shfl_xor(sq, off, 64);
    const float var = sq * (1.0f / 128.0f);
    const float inv = rsqrtf(var + 1e-5f);

    const float2 gm = *(const float2*)(gamma + d);
    const float2 bt = *(const float2*)(beta + d);
    float y0 = d0 * inv * gm.x + bt.x;
    float y1 = d1 * inv * gm.y + bt.y;
    y0 = y0 > 0.0f ? y0 : 0.0f;
    y1 = y1 > 0.0f ? y1 : 0.0f;
    *(float2*)(out + (size_t)n * D + d) = make_float2(y0, y1);
}

// ---------------------------------------------------------------------------
extern "C" void kernel_launch(void* const* d_in, const int* in_sizes, int n_in,
                              void* d_out, int out_size, void* d_ws, size_t ws_size,
                              hipStream_t stream)
{
    const float* x     = (const float*)d_in[0];
    const int*   ei    = (const int*)  d_in[1];
    const float* ea    = (const float*)d_in[2];
    const float* pmask = (const float*)d_in[3];
    const int*   batch = (const int*)  d_in[4];
    const float* We    = (const float*)d_in[5];
    const float* be    = (const float*)d_in[6];
    const float* W1    = (const float*)d_in[7];
    const float* b1    = (const float*)d_in[8];
    const float* W2    = (const float*)d_in[9];
    const float* b2    = (const float*)d_in[10];
    const float* epsp  = (const float*)d_in[11];
    const float* gamma = (const float*)d_in[12];
    const float* beta  = (const float*)d_in[13];
    const float* Wv    = (const float*)d_in[14];
    const float* bv    = (const float*)d_in[15];
    float* out = (float*)d_out;

    const int N = in_sizes[0] / D;     // 50000
    const int E = in_sizes[1] / 2;     // 600000
    const int* src = ei;
    const int* dst = ei + E;

    // Workspace: [deg | agg | psum | pcnt] (single memset), xres (CSR alias),
    // pemb, scan scratch, xb (bf16 copy of x).
    int*   deg  = (int*)d_ws;                           // N
    float* agg  = (float*)(deg + N);                    // N*D
    float* psum = agg + (size_t)N * D;                  // B*K*D
    float* pcnt = psum + (size_t)BGRAPH * K * D;        // B*K
    float* xres = pcnt + (size_t)BGRAPH * K;            // N*D
    float* pemb = xres + (size_t)N * D;                 // B*K*D
    float* extra = pemb + (size_t)BGRAPH * K * D;       // scan scratch (128)
    __hip_bfloat16* xb = (__hip_bfloat16*)(extra + 128);// N*D bf16

    // CSR scratch aliased onto xres (consumed before mlp writes xres)
    int*  cursor = (int*)xres;                          // N
    int4* sde    = (int4*)(((uintptr_t)(cursor + N) + 15) & ~(uintptr_t)15); // E
    int*  bsum   = (int*)extra;                         // 64
    int*  boffs  = bsum + 64;                           // 64

    const int nb = (N + 1023) / 1024;                   // scan blocks (49)
    const int nchunks = (E + CH - 1) / CH;              // 9375

    const size_t zero_bytes =
        ((size_t)N + (size_t)N * D + (size_t)BGRAPH * K * D + BGRAPH * K) * sizeof(float);
    hipMemsetAsync(d_ws, 0, zero_bytes, stream);

    cast_x_kernel<<<(N * D / 8 + 255) / 256, 256, 0, stream>>>(x, xb, N * D);
    hist_kernel<<<(E / 4 + 255) / 256, 256, 0, stream>>>(dst, deg, E);
    scan_partial_kernel<<<nb, 256, 0, stream>>>(deg, bsum, N);
    scan_top_kernel<<<1, 64, 0, stream>>>(bsum, boffs, nb);
    scan_final_kernel<<<nb, 256, 0, stream>>>(deg, boffs, cursor, N);
    scatter_kernel<<<(E + 255) / 256, 256, 0, stream>>>(src, dst, cursor, sde, E);
    gine_reduce_kernel<<<(nchunks + 3) / 4, 256, 0, stream>>>(
        xb, sde, ea, We, be, agg, E);

    mlp_kernel<<<(N + MT_ROWS - 1) / MT_ROWS, 256, 0, stream>>>(
        x, agg, epsp, W1, b1, W2, b2, xres, N);
    pocket_sum_kernel<<<BGRAPH * PPARTS, 128, 0, stream>>>(
        xres, pmask, batch, psum, pcnt, N);
    pocket_emb_kernel<<<BGRAPH, 128, 0, stream>>>(psum, pcnt, Wv, bv, pemb);
    ln_kernel<<<(N + 3) / 4, 256, 0, stream>>>(
        xres, pmask, batch, pemb, gamma, beta, out, N);
}

// Round 7
// 376.399 us; speedup vs baseline: 1.6175x; 1.0775x over previous
//
#include <hip/hip_runtime.h>
#include <hip/hip_bf16.h>
#include <stdint.h>

#define D 128
#define K 8
#define BGRAPH 64
#define CH 64    // edges per wave in gine_reduce
#define GRP 4    // edges per inner group

typedef __attribute__((ext_vector_type(8))) short bf16x8;
typedef __attribute__((ext_vector_type(4))) float f32x4;

__device__ __forceinline__ short f2bf(float f) {
    union { float f; uint32_t u; } v; v.f = f;
    const uint32_t r = (v.u + 0x7fffu + ((v.u >> 16) & 1u)) >> 16;
    return (short)r;
}

// ---------------------------------------------------------------------------
// Stage 0a: cast x to bf16 for the gather path
// ---------------------------------------------------------------------------
__global__ __launch_bounds__(256) void cast_x_kernel(
    const float* __restrict__ x, __hip_bfloat16* __restrict__ xb, int n)
{
    const int i = (blockIdx.x * 256 + threadIdx.x) * 8;
    if (i + 8 > n) return;
    const float4 a = *(const float4*)(x + i);
    const float4 b = *(const float4*)(x + i + 4);
    __hip_bfloat16 v[8];
    v[0] = __float2bfloat16(a.x); v[1] = __float2bfloat16(a.y);
    v[2] = __float2bfloat16(a.z); v[3] = __float2bfloat16(a.w);
    v[4] = __float2bfloat16(b.x); v[5] = __float2bfloat16(b.y);
    v[6] = __float2bfloat16(b.z); v[7] = __float2bfloat16(b.w);
    *(uint4*)(xb + i) = *(const uint4*)v;
}

// ---------------------------------------------------------------------------
// Stage 0b: cast W1/W2 to transposed bf16 (wbt[n][k] = W[k][n]) for MFMA B-frags
// blockIdx: [0,128) -> W1 col n; [128,256) -> W2 col n
// ---------------------------------------------------------------------------
__global__ __launch_bounds__(128) void cast_w_kernel(
    const float* __restrict__ W1, const float* __restrict__ W2,
    short* __restrict__ wb1t, short* __restrict__ wb2t)
{
    const int which = blockIdx.x >> 7;
    const int n = blockIdx.x & 127;
    const int k = threadIdx.x;
    const float* W = which ? W2 : W1;
    short* O = which ? wb2t : wb1t;
    O[n * D + k] = f2bf(W[(size_t)k * D + n]);
}

// ---------------------------------------------------------------------------
// Stage 1a: in-degree histogram over dst
// ---------------------------------------------------------------------------
__global__ __launch_bounds__(256) void hist_kernel(
    const int* __restrict__ dst, int* __restrict__ deg, int E)
{
    const int i = (blockIdx.x * 256 + threadIdx.x) * 4;
    if (i + 4 <= E) {
        const int4 v = *(const int4*)(dst + i);
        atomicAdd(&deg[v.x], 1);
        atomicAdd(&deg[v.y], 1);
        atomicAdd(&deg[v.z], 1);
        atomicAdd(&deg[v.w], 1);
    } else {
        for (int j = i; j < E; ++j) atomicAdd(&deg[dst[j]], 1);
    }
}

// ---------------------------------------------------------------------------
// Stage 1b: three-phase exclusive scan of deg[N] -> cursor[N]
// ---------------------------------------------------------------------------
__global__ __launch_bounds__(256) void scan_partial_kernel(
    const int* __restrict__ deg, int* __restrict__ bsum, int N)
{
    const int t = threadIdx.x;
    const int base = (blockIdx.x * 256 + t) * 4;
    int s = 0;
    if (base + 4 <= N) {
        const int4 v = *(const int4*)(deg + base);
        s = v.x + v.y + v.z + v.w;
    } else {
        for (int j = base; j < N; ++j) s += deg[j];
    }
    __shared__ int red[256];
    red[t] = s;
    __syncthreads();
    for (int off = 128; off; off >>= 1) {
        if (t < off) red[t] += red[t + off];
        __syncthreads();
    }
    if (t == 0) bsum[blockIdx.x] = red[0];
}

__global__ __launch_bounds__(64) void scan_top_kernel(
    const int* __restrict__ bsum, int* __restrict__ boffs, int nb)
{
    __shared__ int sh[64];
    const int t = threadIdx.x;
    const int v = (t < nb) ? bsum[t] : 0;
    sh[t] = v;
    __syncthreads();
    for (int off = 1; off < 64; off <<= 1) {
        const int u = (t >= off) ? sh[t - off] : 0;
        __syncthreads();
        sh[t] += u;
        __syncthreads();
    }
    if (t < nb) boffs[t] = sh[t] - v;      // exclusive
}

__global__ __launch_bounds__(256) void scan_final_kernel(
    const int* __restrict__ deg, const int* __restrict__ boffs,
    int* __restrict__ cursor, int N)
{
    const int t = threadIdx.x;
    const int base = (blockIdx.x * 256 + t) * 4;
    int v0 = 0, v1 = 0, v2 = 0, v3 = 0;
    if (base + 4 <= N) {
        const int4 v = *(const int4*)(deg + base);
        v0 = v.x; v1 = v.y; v2 = v.z; v3 = v.w;
    } else {
        if (base     < N) v0 = deg[base];
        if (base + 1 < N) v1 = deg[base + 1];
        if (base + 2 < N) v2 = deg[base + 2];
        if (base + 3 < N) v3 = deg[base + 3];
    }
    const int s = v0 + v1 + v2 + v3;
    __shared__ int sh[256];
    sh[t] = s;
    __syncthreads();
    for (int off = 1; off < 256; off <<= 1) {
        const int u = (t >= off) ? sh[t - off] : 0;
        __syncthreads();
        sh[t] += u;
        __syncthreads();
    }
    int ex = boffs[blockIdx.x] + sh[t] - s;
    if (base < N)     { cursor[base]     = ex; } ex += v0;
    if (base + 1 < N) { cursor[base + 1] = ex; } ex += v1;
    if (base + 2 < N) { cursor[base + 2] = ex; } ex += v2;
    if (base + 3 < N) { cursor[base + 3] = ex; }
}

// ---------------------------------------------------------------------------
// Stage 1c: scatter (src, dst, eid) as one int4 into dst-grouped order
// ---------------------------------------------------------------------------
__global__ __launch_bounds__(256) void scatter_kernel(
    const int* __restrict__ src, const int* __restrict__ dst,
    int* __restrict__ cursor, int4* __restrict__ sde, int E)
{
    const int i = blockIdx.x * 256 + threadIdx.x;
    if (i < E) {
        const int sv = src[i];
        const int dv = dst[i];
        const int p = atomicAdd(&cursor[dv], 1);
        sde[p] = make_int4(sv, dv, i, 0);
    }
}

// ---------------------------------------------------------------------------
// Stage 1d: edge-parallel gather-reduce; scalar metadata/ea, bf16 x gathers,
// meta prefetched 2 groups ahead, x 1 group ahead.
// ---------------------------------------------------------------------------
__device__ __forceinline__ void flush_row(
    float* __restrict__ agg, int node, int d, float2 acc, int first, int last)
{
    float* p = agg + (size_t)node * D + d;
    if (node == first || node == last) {
        if (acc.x != 0.f) atomicAdd(p,     acc.x);
        if (acc.y != 0.f) atomicAdd(p + 1, acc.y);
    } else {
        *(float2*)p = acc;
    }
}

__global__ __launch_bounds__(256) void gine_reduce_kernel(
    const __hip_bfloat16* __restrict__ xb, const int4* __restrict__ sde,
    const float* __restrict__ ea, const float* __restrict__ We,
    const float* __restrict__ be, float* __restrict__ agg, int E)
{
    const int wave = threadIdx.x >> 6;
    const int lane = threadIdx.x & 63;
    const int chunk = __builtin_amdgcn_readfirstlane(blockIdx.x * 4 + wave);
    const int e0 = chunk * CH;
    if (e0 >= E) return;
    const int d = lane * 2;
    const int NG = CH / GRP;

    float2 w[16];
    #pragma unroll
    for (int j = 0; j < 16; ++j) w[j] = *(const float2*)(We + j * D + d);
    const float2 bb = *(const float2*)(be + d);

    int4 mcur[GRP], mnext[GRP];
    #pragma unroll
    for (int j = 0; j < GRP; ++j) mcur[j] = sde[e0 + j];
    #pragma unroll
    for (int j = 0; j < GRP; ++j) mnext[j] = sde[e0 + GRP + j];
    __hip_bfloat162 xcur[GRP];
    #pragma unroll
    for (int j = 0; j < GRP; ++j)
        xcur[j] = *(const __hip_bfloat162*)(xb + (size_t)mcur[j].x * D + d);

    const int first = mcur[0].y;
    const int last  = sde[e0 + CH - 1].y;

    float2 acc = make_float2(0.f, 0.f);
    int cur = first;

    for (int g = 0; g < NG; ++g) {
        int4 mnn[GRP] = {};
        __hip_bfloat162 xn[GRP] = {};
        if (g + 2 < NG) {
            #pragma unroll
            for (int j = 0; j < GRP; ++j) mnn[j] = sde[e0 + (g + 2) * GRP + j];
        }
        if (g + 1 < NG) {
            #pragma unroll
            for (int j = 0; j < GRP; ++j)
                xn[j] = *(const __hip_bfloat162*)(xb + (size_t)mnext[j].x * D + d);
        }

        float4 A[GRP][4];
        #pragma unroll
        for (int j = 0; j < GRP; ++j) {
            const float4* p = (const float4*)(ea + (size_t)mcur[j].z * 16);
            A[j][0] = p[0]; A[j][1] = p[1]; A[j][2] = p[2]; A[j][3] = p[3];
        }

        #pragma unroll
        for (int j = 0; j < GRP; ++j) {
            const int dk = mcur[j].y;
            if (dk != cur) {
                flush_row(agg, cur, d, acc, first, last);
                acc = make_float2(0.f, 0.f);
                cur = dk;
            }
            float m0 = bb.x + __bfloat162float(xcur[j].x);
            float m1 = bb.y + __bfloat162float(xcur[j].y);
            const float av[16] = {
                A[j][0].x, A[j][0].y, A[j][0].z, A[j][0].w,
                A[j][1].x, A[j][1].y, A[j][1].z, A[j][1].w,
                A[j][2].x, A[j][2].y, A[j][2].z, A[j][2].w,
                A[j][3].x, A[j][3].y, A[j][3].z, A[j][3].w};
            #pragma unroll
            for (int jj = 0; jj < 16; ++jj) {
                m0 += av[jj] * w[jj].x;
                m1 += av[jj] * w[jj].y;
            }
            acc.x += m0 > 0.f ? m0 : 0.f;
            acc.y += m1 > 0.f ? m1 : 0.f;
        }

        #pragma unroll
        for (int j = 0; j < GRP; ++j) {
            mcur[j] = mnext[j]; mnext[j] = mnn[j]; xcur[j] = xn[j];
        }
    }
    flush_row(agg, cur, d, acc, first, last);
}

// ---------------------------------------------------------------------------
// Stage 2: MFMA MLP.  x_res = relu(h@W1+b1)@W2+b2,  h = (1+eps)*x + agg.
// Block = 64 rows, 4 waves; wave owns 16 rows. h fp32 in LDS (stride 132).
// mfma_f32_16x16x32_bf16; A[m=lane&15][k=quad*8+j]; B[k][n=lane&15] from
// transposed bf16 W (contiguous 16B); C/D col=lane&15,row=quad*4+reg.
// t overwrites h in place (wave-private rows) -> NO inter-layer barrier.
// ---------------------------------------------------------------------------
#define MROWS 64
#define HSTR  132
__global__ __launch_bounds__(256) void mlp_mfma_kernel(
    const float* __restrict__ x, const float* __restrict__ agg,
    const float* __restrict__ epsp,
    const short* __restrict__ wb1t, const float* __restrict__ b1,
    const short* __restrict__ wb2t, const float* __restrict__ b2,
    float* __restrict__ xres, int N)
{
    __shared__ float hsh[MROWS * HSTR];   // 33.8 KB
    const int row0 = blockIdx.x * MROWS;
    const float ep = 1.0f + epsp[0];

    for (int i = threadIdx.x; i < MROWS * D / 4; i += 256) {
        const int flat = i * 4;
        const int r = flat >> 7;
        const int c = flat & (D - 1);
        const int row = row0 + r;
        float4 hv = make_float4(0.f, 0.f, 0.f, 0.f);
        if (row < N) {
            const float4 xv = *(const float4*)(x   + (size_t)row * D + c);
            const float4 av = *(const float4*)(agg + (size_t)row * D + c);
            hv = make_float4(ep * xv.x + av.x, ep * xv.y + av.y,
                             ep * xv.z + av.z, ep * xv.w + av.w);
        }
        *(float4*)(hsh + r * HSTR + c) = hv;
    }
    __syncthreads();

    const int lane = threadIdx.x & 63;
    const int wrow = (threadIdx.x >> 6) * 16;  // wave's 16-row window
    const int m = lane & 15;                   // A row / B col / C col
    const int q = lane >> 4;                   // quad

    f32x4 acc[8];

    // ---- layer 1 ----
    #pragma unroll
    for (int ct = 0; ct < 8; ++ct) {
        const float b = b1[ct * 16 + m];
        acc[ct] = (f32x4){b, b, b, b};
    }
    #pragma unroll
    for (int ks = 0; ks < 4; ++ks) {
        const float* ap = hsh + (wrow + m) * HSTR + ks * 32 + q * 8;
        float av[8];
        *(float4*)(av)     = *(const float4*)ap;
        *(float4*)(av + 4) = *(const float4*)(ap + 4);
        bf16x8 a;
        #pragma unroll
        for (int j = 0; j < 8; ++j) a[j] = f2bf(av[j]);
        #pragma unroll
        for (int ct = 0; ct < 8; ++ct) {
            const bf16x8 b = *(const bf16x8*)(wb1t + (ct * 16 + m) * D + ks * 32 + q * 8);
            acc[ct] = __builtin_amdgcn_mfma_f32_16x16x32_bf16(a, b, acc[ct], 0, 0, 0);
        }
    }
    // relu(t) -> overwrite hsh rows of this wave (wave-private, no barrier)
    #pragma unroll
    for (int ct = 0; ct < 8; ++ct)
        #pragma unroll
        for (int r = 0; r < 4; ++r) {
            const float v = acc[ct][r];
            hsh[(wrow + q * 4 + r) * HSTR + ct * 16 + m] = v > 0.f ? v : 0.f;
        }

    // ---- layer 2 ----
    #pragma unroll
    for (int ct = 0; ct < 8; ++ct) {
        const float b = b2[ct * 16 + m];
        acc[ct] = (f32x4){b, b, b, b};
    }
    #pragma unroll
    for (int ks = 0; ks < 4; ++ks) {
        const float* ap = hsh + (wrow + m) * HSTR + ks * 32 + q * 8;
        float av[8];
        *(float4*)(av)     = *(const float4*)ap;
        *(float4*)(av + 4) = *(const float4*)(ap + 4);
        bf16x8 a;
        #pragma unroll
        for (int j = 0; j < 8; ++j) a[j] = f2bf(av[j]);
        #pragma unroll
        for (int ct = 0; ct < 8; ++ct) {
            const bf16x8 b = *(const bf16x8*)(wb2t + (ct * 16 + m) * D + ks * 32 + q * 8);
            acc[ct] = __builtin_amdgcn_mfma_f32_16x16x32_bf16(a, b, acc[ct], 0, 0, 0);
        }
    }
    // epilogue: scattered dword stores (16-lane 64B segments)
    #pragma unroll
    for (int r = 0; r < 4; ++r) {
        const int row = row0 + wrow + q * 4 + r;
        if (row < N) {
            #pragma unroll
            for (int ct = 0; ct < 8; ++ct)
                xres[(size_t)row * D + ct * 16 + m] = acc[ct][r];
        }
    }
}

// ---------------------------------------------------------------------------
// Stage 3: per-(graph,pocket) masked sums
// ---------------------------------------------------------------------------
#define PPARTS 32
__global__ __launch_bounds__(128) void pocket_sum_kernel(
    const float* __restrict__ xres, const float* __restrict__ pmask,
    const int* __restrict__ batch,
    float* __restrict__ psum, float* __restrict__ pcnt, int N)
{
    const int g = blockIdx.x / PPARTS;
    const int part = blockIdx.x % PPARTS;

    int lo, hi;
    {
        int l = 0, r = N;
        while (l < r) { int m = (l + r) >> 1; if (batch[m] < g) l = m + 1; else r = m; }
        lo = l;
        r = N;
        while (l < r) { int m = (l + r) >> 1; if (batch[m] < g + 1) l = m + 1; else r = m; }
        hi = l;
    }
    const int cnt = hi - lo;
    const int per = (cnt + PPARTS - 1) / PPARTS;
    const int s = lo + part * per;
    const int e = min(s + per, hi);

    const int d = threadIdx.x;
    float acc[K];
    #pragma unroll
    for (int k = 0; k < K; ++k) acc[k] = 0.0f;
    float c = 0.0f;

    for (int n = s; n < e; ++n) {
        const float xv = xres[(size_t)n * D + d];
        const float4 m0 = *(const float4*)(pmask + (size_t)n * K);
        const float4 m1 = *(const float4*)(pmask + (size_t)n * K + 4);
        acc[0] += m0.x * xv; acc[1] += m0.y * xv;
        acc[2] += m0.z * xv; acc[3] += m0.w * xv;
        acc[4] += m1.x * xv; acc[5] += m1.y * xv;
        acc[6] += m1.z * xv; acc[7] += m1.w * xv;
        if (d < K) c += pmask[(size_t)n * K + d];
    }
    #pragma unroll
    for (int k = 0; k < K; ++k)
        atomicAdd(&psum[(size_t)g * (K * D) + k * D + d], acc[k]);
    if (d < K) atomicAdd(&pcnt[g * K + d], c);
}

// ---------------------------------------------------------------------------
// Stage 4: pocket_emb = (psum / (pcnt + 1e-9)) @ Wv + bv
// ---------------------------------------------------------------------------
__global__ __launch_bounds__(128) void pocket_emb_kernel(
    const float* __restrict__ psum, const float* __restrict__ pcnt,
    const float* __restrict__ Wv, const float* __restrict__ bv,
    float* __restrict__ pemb)
{
    __shared__ float smean[K * D];
    __shared__ float scnt[K];
    const int g = blockIdx.x;
    const int d = threadIdx.x;
    if (d < K) scnt[d] = pcnt[g * K + d];
    __syncthreads();
    #pragma unroll
    for (int k = 0; k < K; ++k)
        smean[k * D + d] = psum[(size_t)g * (K * D) + k * D + d] / (scnt[k] + 1e-9f);
    __syncthreads();

    float acc[K];
    const float bvv = bv[d];
    #pragma unroll
    for (int k = 0; k < K; ++k) acc[k] = bvv;
    for (int j = 0; j < D; ++j) {
        const float w = Wv[j * D + d];
        #pragma unroll
        for (int k = 0; k < K; ++k) acc[k] += smean[k * D + j] * w;
    }
    #pragma unroll
    for (int k = 0; k < K; ++k)
        pemb[(size_t)g * (K * D) + k * D + d] = acc[k];
}

// ---------------------------------------------------------------------------
// Stage 5: feedback gather + LayerNorm + ReLU. One wave per node.
// ---------------------------------------------------------------------------
__global__ __launch_bounds__(256) void ln_kernel(
    const float* __restrict__ xres, const float* __restrict__ pmask,
    const int* __restrict__ batch, const float* __restrict__ pemb,
    const float* __restrict__ gamma, const float* __restrict__ beta,
    float* __restrict__ out, int N)
{
    const int wave = threadIdx.x >> 6;
    const int lane = threadIdx.x & 63;
    const int n = blockIdx.x * 4 + wave;
    if (n >= N) return;
    const int d = lane * 2;

    float2 v = *(const float2*)(xres + (size_t)n * D + d);
    const int g = batch[n];
    const float* pe = pemb + (size_t)g * (K * D);
    const float4 m0 = *(const float4*)(pmask + (size_t)n * K);
    const float4 m1 = *(const float4*)(pmask + (size_t)n * K + 4);
    const float mk[K] = {m0.x, m0.y, m0.z, m0.w, m1.x, m1.y, m1.z, m1.w};
    #pragma unroll
    for (int k = 0; k < K; ++k) {
        if (mk[k] != 0.0f) {   // wave-uniform branch
            const float2 p = *(const float2*)(pe + k * D + d);
            v.x += mk[k] * p.x;
            v.y += mk[k] * p.y;
        }
    }

    float s = v.x + v.y;
    #pragma unroll
    for (int off = 32; off; off >>= 1) s += __shfl_xor(s, off, 64);
    const float mu = s * (1.0f / 128.0f);
    const float d0 = v.x - mu, d1 = v.y - mu;
    float sq = d0 * d0 + d1 * d1;
    #pragma unroll
    for (int off = 32; off; off >>= 1) sq += __shfl_xor(sq, off, 64);
    const float var = sq * (1.0f / 128.0f);
    const float inv = rsqrtf(var + 1e-5f);

    const float2 gm = *(const float2*)(gamma + d);
    const float2 bt = *(const float2*)(beta + d);
    float y0 = d0 * inv * gm.x + bt.x;
    float y1 = d1 * inv * gm.y + bt.y;
    y0 = y0 > 0.0f ? y0 : 0.0f;
    y1 = y1 > 0.0f ? y1 : 0.0f;
    *(float2*)(out + (size_t)n * D + d) = make_float2(y0, y1);
}

// ---------------------------------------------------------------------------
extern "C" void kernel_launch(void* const* d_in, const int* in_sizes, int n_in,
                              void* d_out, int out_size, void* d_ws, size_t ws_size,
                              hipStream_t stream)
{
    const float* x     = (const float*)d_in[0];
    const int*   ei    = (const int*)  d_in[1];
    const float* ea    = (const float*)d_in[2];
    const float* pmask = (const float*)d_in[3];
    const int*   batch = (const int*)  d_in[4];
    const float* We    = (const float*)d_in[5];
    const float* be    = (const float*)d_in[6];
    const float* W1    = (const float*)d_in[7];
    const float* b1    = (const float*)d_in[8];
    const float* W2    = (const float*)d_in[9];
    const float* b2    = (const float*)d_in[10];
    const float* epsp  = (const float*)d_in[11];
    const float* gamma = (const float*)d_in[12];
    const float* beta  = (const float*)d_in[13];
    const float* Wv    = (const float*)d_in[14];
    const float* bv    = (const float*)d_in[15];
    float* out = (float*)d_out;

    const int N = in_sizes[0] / D;     // 50000
    const int E = in_sizes[1] / 2;     // 600000
    const int* src = ei;
    const int* dst = ei + E;

    // Workspace: [deg | agg | psum | pcnt] (single memset), xres (CSR alias),
    // pemb, scan scratch, xb (bf16 x), wb1t/wb2t (bf16 transposed weights).
    int*   deg  = (int*)d_ws;                           // N
    float* agg  = (float*)(deg + N);                    // N*D
    float* psum = agg + (size_t)N * D;                  // B*K*D
    float* pcnt = psum + (size_t)BGRAPH * K * D;        // B*K
    float* xres = pcnt + (size_t)BGRAPH * K;            // N*D
    float* pemb = xres + (size_t)N * D;                 // B*K*D
    float* extra = pemb + (size_t)BGRAPH * K * D;       // scan scratch (128)
    __hip_bfloat16* xb = (__hip_bfloat16*)(extra + 128);// N*D bf16
    short* wb1t = (short*)(xb + (size_t)N * D);         // D*D bf16
    short* wb2t = wb1t + (size_t)D * D;                 // D*D bf16

    // CSR scratch aliased onto xres (consumed before mlp writes xres)
    int*  cursor = (int*)xres;                          // N
    int4* sde    = (int4*)(((uintptr_t)(cursor + N) + 15) & ~(uintptr_t)15); // E
    int*  bsum   = (int*)extra;                         // 64
    int*  boffs  = bsum + 64;                           // 64

    const int nb = (N + 1023) / 1024;                   // scan blocks (49)
    const int nchunks = (E + CH - 1) / CH;              // 9375

    const size_t zero_bytes =
        ((size_t)N + (size_t)N * D + (size_t)BGRAPH * K * D + BGRAPH * K) * sizeof(float);
    hipMemsetAsync(d_ws, 0, zero_bytes, stream);

    cast_x_kernel<<<(N * D / 8 + 255) / 256, 256, 0, stream>>>(x, xb, N * D);
    cast_w_kernel<<<256, 128, 0, stream>>>(W1, W2, wb1t, wb2t);
    hist_kernel<<<(E / 4 + 255) / 256, 256, 0, stream>>>(dst, deg, E);
    scan_partial_kernel<<<nb, 256, 0, stream>>>(deg, bsum, N);
    scan_top_kernel<<<1, 64, 0, stream>>>(bsum, boffs, nb);
    scan_final_kernel<<<nb, 256, 0, stream>>>(deg, boffs, cursor, N);
    scatter_kernel<<<(E + 255) / 256, 256, 0, stream>>>(src, dst, cursor, sde, E);
    gine_reduce_kernel<<<(nchunks + 3) / 4, 256, 0, stream>>>(
        xb, sde, ea, We, be, agg, E);

    mlp_mfma_kernel<<<(N + MROWS - 1) / MROWS, 256, 0, stream>>>(
        x, agg, epsp, wb1t, b1, wb2t, b2, xres, N);
    pocket_sum_kernel<<<BGRAPH * PPARTS, 128, 0, stream>>>(
        xres, pmask, batch, psum, pcnt, N);
    pocket_emb_kernel<<<BGRAPH, 128, 0, stream>>>(psum, pcnt, Wv, bv, pemb);
    ln_kernel<<<(N + 3) / 4, 256, 0, stream>>>(
        xres, pmask, batch, pemb, gamma, beta, out, N);
}

// Round 8
// 367.738 us; speedup vs baseline: 1.6556x; 1.0236x over previous
//
#include <hip/hip_runtime.h>
#include <hip/hip_bf16.h>
#include <stdint.h>

#define D 128
#define K 8
#define BGRAPH 64
#define CH 64    // edges per wave in gine_reduce
#define GRP 4    // edges per inner group

typedef __attribute__((ext_vector_type(8))) short bf16x8;
typedef __attribute__((ext_vector_type(4))) float f32x4;

__device__ __forceinline__ short f2bf(float f) {
    union { float f; uint32_t u; } v; v.f = f;
    const uint32_t r = (v.u + 0x7fffu + ((v.u >> 16) & 1u)) >> 16;
    return (short)r;
}
__device__ __forceinline__ float bflo(uint32_t u) {
    union { uint32_t u; float f; } v; v.u = u << 16; return v.f;
}
__device__ __forceinline__ float bfhi(uint32_t u) {
    union { uint32_t u; float f; } v; v.u = u & 0xffff0000u; return v.f;
}

// ---------------------------------------------------------------------------
// Stage 0 (fused prep): cast x->bf16, ea->bf16, W1/W2->bf16 transposed,
// and dst in-degree histogram. Disjoint blockIdx ranges.
// ---------------------------------------------------------------------------
__global__ __launch_bounds__(256) void prep_kernel(
    const float* __restrict__ x, const float* __restrict__ ea,
    const float* __restrict__ W1, const float* __restrict__ W2,
    const int* __restrict__ dst,
    __hip_bfloat16* __restrict__ xb, short* __restrict__ eab,
    short* __restrict__ wb1t, short* __restrict__ wb2t,
    int* __restrict__ deg,
    int NX, int NEA, int E, int NBX, int NBE, int NBW)
{
    const int b = blockIdx.x;
    const int t = threadIdx.x;
    if (b < NBX) {
        // ---- cast x (8 floats/thread) ----
        const int i = b * 2048 + t * 8;
        if (i + 8 <= NX) {
            const float4 a = *(const float4*)(x + i);
            const float4 c = *(const float4*)(x + i + 4);
            short v[8];
            v[0] = f2bf(a.x); v[1] = f2bf(a.y); v[2] = f2bf(a.z); v[3] = f2bf(a.w);
            v[4] = f2bf(c.x); v[5] = f2bf(c.y); v[6] = f2bf(c.z); v[7] = f2bf(c.w);
            *(uint4*)((short*)xb + i) = *(const uint4*)v;
        }
    } else if (b < NBX + NBE) {
        // ---- cast ea (8 floats/thread) ----
        const int i = (b - NBX) * 2048 + t * 8;
        if (i + 8 <= NEA) {
            const float4 a = *(const float4*)(ea + i);
            const float4 c = *(const float4*)(ea + i + 4);
            short v[8];
            v[0] = f2bf(a.x); v[1] = f2bf(a.y); v[2] = f2bf(a.z); v[3] = f2bf(a.w);
            v[4] = f2bf(c.x); v[5] = f2bf(c.y); v[6] = f2bf(c.z); v[7] = f2bf(c.w);
            *(uint4*)(eab + i) = *(const uint4*)v;
        }
    } else if (b < NBX + NBE + NBW) {
        // ---- W transpose cast (1 elem/thread) ----
        const int idx = (b - NBX - NBE) * 256 + t;
        const int which = idx >> 14;           // 0: W1, 1: W2
        const int rem = idx & 16383;
        const int n = rem >> 7;
        const int k = rem & 127;
        const float* W = which ? W2 : W1;
        short* O = which ? wb2t : wb1t;
        O[n * D + k] = f2bf(W[(size_t)k * D + n]);
    } else {
        // ---- dst histogram (4 edges/thread) ----
        const int i = ((b - NBX - NBE - NBW) * 256 + t) * 4;
        if (i + 4 <= E) {
            const int4 v = *(const int4*)(dst + i);
            atomicAdd(&deg[v.x], 1);
            atomicAdd(&deg[v.y], 1);
            atomicAdd(&deg[v.z], 1);
            atomicAdd(&deg[v.w], 1);
        } else {
            for (int j = i; j < E; ++j) atomicAdd(&deg[dst[j]], 1);
        }
    }
}

// ---------------------------------------------------------------------------
// Stage 1b: three-phase exclusive scan of deg[N] -> cursor[N]
// ---------------------------------------------------------------------------
__global__ __launch_bounds__(256) void scan_partial_kernel(
    const int* __restrict__ deg, int* __restrict__ bsum, int N)
{
    const int t = threadIdx.x;
    const int base = (blockIdx.x * 256 + t) * 4;
    int s = 0;
    if (base + 4 <= N) {
        const int4 v = *(const int4*)(deg + base);
        s = v.x + v.y + v.z + v.w;
    } else {
        for (int j = base; j < N; ++j) s += deg[j];
    }
    __shared__ int red[256];
    red[t] = s;
    __syncthreads();
    for (int off = 128; off; off >>= 1) {
        if (t < off) red[t] += red[t + off];
        __syncthreads();
    }
    if (t == 0) bsum[blockIdx.x] = red[0];
}

__global__ __launch_bounds__(64) void scan_top_kernel(
    const int* __restrict__ bsum, int* __restrict__ boffs, int nb)
{
    __shared__ int sh[64];
    const int t = threadIdx.x;
    const int v = (t < nb) ? bsum[t] : 0;
    sh[t] = v;
    __syncthreads();
    for (int off = 1; off < 64; off <<= 1) {
        const int u = (t >= off) ? sh[t - off] : 0;
        __syncthreads();
        sh[t] += u;
        __syncthreads();
    }
    if (t < nb) boffs[t] = sh[t] - v;      // exclusive
}

__global__ __launch_bounds__(256) void scan_final_kernel(
    const int* __restrict__ deg, const int* __restrict__ boffs,
    int* __restrict__ cursor, int N)
{
    const int t = threadIdx.x;
    const int base = (blockIdx.x * 256 + t) * 4;
    int v0 = 0, v1 = 0, v2 = 0, v3 = 0;
    if (base + 4 <= N) {
        const int4 v = *(const int4*)(deg + base);
        v0 = v.x; v1 = v.y; v2 = v.z; v3 = v.w;
    } else {
        if (base     < N) v0 = deg[base];
        if (base + 1 < N) v1 = deg[base + 1];
        if (base + 2 < N) v2 = deg[base + 2];
        if (base + 3 < N) v3 = deg[base + 3];
    }
    const int s = v0 + v1 + v2 + v3;
    __shared__ int sh[256];
    sh[t] = s;
    __syncthreads();
    for (int off = 1; off < 256; off <<= 1) {
        const int u = (t >= off) ? sh[t - off] : 0;
        __syncthreads();
        sh[t] += u;
        __syncthreads();
    }
    int ex = boffs[blockIdx.x] + sh[t] - s;
    if (base < N)     { cursor[base]     = ex; } ex += v0;
    if (base + 1 < N) { cursor[base + 1] = ex; } ex += v1;
    if (base + 2 < N) { cursor[base + 2] = ex; } ex += v2;
    if (base + 3 < N) { cursor[base + 3] = ex; }
}

// ---------------------------------------------------------------------------
// Stage 1c: scatter packed (src|dst<<16, eid) into dst-grouped order
// ---------------------------------------------------------------------------
__global__ __launch_bounds__(256) void scatter_kernel(
    const int* __restrict__ src, const int* __restrict__ dst,
    int* __restrict__ cursor, uint2* __restrict__ md, int E)
{
    const int i = blockIdx.x * 256 + threadIdx.x;
    if (i < E) {
        const unsigned sv = (unsigned)src[i];
        const unsigned dv = (unsigned)dst[i];
        const int p = atomicAdd(&cursor[dv], 1);
        md[p] = make_uint2(sv | (dv << 16), (unsigned)i);
    }
}

// ---------------------------------------------------------------------------
// Stage 1d: edge-parallel gather-reduce. Packed scalar metadata, bf16 scalar
// ea rows (unpacked via uniform SALU shifts), bf16 x gathers. Pipeline:
// meta 2 groups ahead, ea + x 1 group ahead.
// ---------------------------------------------------------------------------
__device__ __forceinline__ void flush_row(
    float* __restrict__ agg, int node, int d, float2 acc, int first, int last)
{
    float* p = agg + (size_t)node * D + d;
    if (node == first || node == last) {
        if (acc.x != 0.f) atomicAdd(p,     acc.x);
        if (acc.y != 0.f) atomicAdd(p + 1, acc.y);
    } else {
        *(float2*)p = acc;
    }
}

__global__ __launch_bounds__(256) void gine_reduce_kernel(
    const __hip_bfloat16* __restrict__ xb, const uint2* __restrict__ md,
    const short* __restrict__ eab, const float* __restrict__ We,
    const float* __restrict__ be, float* __restrict__ agg, int E)
{
    const int wave = threadIdx.x >> 6;
    const int lane = threadIdx.x & 63;
    const int chunk = __builtin_amdgcn_readfirstlane(blockIdx.x * 4 + wave);
    const int e0 = chunk * CH;
    if (e0 >= E) return;
    const int d = lane * 2;
    const int NG = CH / GRP;

    float2 w[16];
    #pragma unroll
    for (int j = 0; j < 16; ++j) w[j] = *(const float2*)(We + j * D + d);
    const float2 bb = *(const float2*)(be + d);

    // prologue: meta groups 0,1; ea + x group 0
    uint2 mcur[GRP], mnext[GRP];
    #pragma unroll
    for (int j = 0; j < GRP; ++j) mcur[j] = md[e0 + j];
    #pragma unroll
    for (int j = 0; j < GRP; ++j) mnext[j] = md[e0 + GRP + j];
    uint4 eacur[GRP][2];
    #pragma unroll
    for (int j = 0; j < GRP; ++j) {
        const uint4* p = (const uint4*)(eab + (size_t)mcur[j].y * 16);
        eacur[j][0] = p[0]; eacur[j][1] = p[1];
    }
    __hip_bfloat162 xcur[GRP];
    #pragma unroll
    for (int j = 0; j < GRP; ++j)
        xcur[j] = *(const __hip_bfloat162*)(xb + (size_t)(mcur[j].x & 0xffffu) * D + d);

    const int first = (int)(mcur[0].x >> 16);
    const int last  = (int)(md[e0 + CH - 1].x >> 16);

    float2 acc = make_float2(0.f, 0.f);
    int cur = first;

    for (int g = 0; g < NG; ++g) {
        // prefetch: meta g+2, ea + x for g+1
        uint2 mnn[GRP] = {};
        uint4 ean[GRP][2] = {};
        __hip_bfloat162 xn[GRP] = {};
        if (g + 2 < NG) {
            #pragma unroll
            for (int j = 0; j < GRP; ++j) mnn[j] = md[e0 + (g + 2) * GRP + j];
        }
        if (g + 1 < NG) {
            #pragma unroll
            for (int j = 0; j < GRP; ++j) {
                const uint4* p = (const uint4*)(eab + (size_t)mnext[j].y * 16);
                ean[j][0] = p[0]; ean[j][1] = p[1];
            }
            #pragma unroll
            for (int j = 0; j < GRP; ++j)
                xn[j] = *(const __hip_bfloat162*)(xb + (size_t)(mnext[j].x & 0xffffu) * D + d);
        }

        #pragma unroll
        for (int j = 0; j < GRP; ++j) {
            const int dk = (int)(mcur[j].x >> 16);
            if (dk != cur) {                  // wave-uniform scalar branch
                flush_row(agg, cur, d, acc, first, last);
                acc = make_float2(0.f, 0.f);
                cur = dk;
            }
            float m0 = bb.x + __bfloat162float(xcur[j].x);
            float m1 = bb.y + __bfloat162float(xcur[j].y);
            const uint4 ua = eacur[j][0];
            const uint4 ub = eacur[j][1];
            const float av[16] = {
                bflo(ua.x), bfhi(ua.x), bflo(ua.y), bfhi(ua.y),
                bflo(ua.z), bfhi(ua.z), bflo(ua.w), bfhi(ua.w),
                bflo(ub.x), bfhi(ub.x), bflo(ub.y), bfhi(ub.y),
                bflo(ub.z), bfhi(ub.z), bflo(ub.w), bfhi(ub.w)};
            #pragma unroll
            for (int jj = 0; jj < 16; ++jj) {
                m0 += av[jj] * w[jj].x;
                m1 += av[jj] * w[jj].y;
            }
            acc.x += m0 > 0.f ? m0 : 0.f;
            acc.y += m1 > 0.f ? m1 : 0.f;
        }

        #pragma unroll
        for (int j = 0; j < GRP; ++j) {
            mcur[j] = mnext[j]; mnext[j] = mnn[j];
            eacur[j][0] = ean[j][0]; eacur[j][1] = ean[j][1];
            xcur[j] = xn[j];
        }
    }
    flush_row(agg, cur, d, acc, first, last);
}

// ---------------------------------------------------------------------------
// Stage 2: MFMA MLP.  x_res = relu(h@W1+b1)@W2+b2,  h = (1+eps)*x + agg.
// Block = 64 rows, 4 waves; wave owns 16 rows; t overwrites h in place.
// ---------------------------------------------------------------------------
#define MROWS 64
#define HSTR  132
__global__ __launch_bounds__(256) void mlp_mfma_kernel(
    const float* __restrict__ x, const float* __restrict__ agg,
    const float* __restrict__ epsp,
    const short* __restrict__ wb1t, const float* __restrict__ b1,
    const short* __restrict__ wb2t, const float* __restrict__ b2,
    float* __restrict__ xres, int N)
{
    __shared__ float hsh[MROWS * HSTR];   // 33.8 KB
    const int row0 = blockIdx.x * MROWS;
    const float ep = 1.0f + epsp[0];

    for (int i = threadIdx.x; i < MROWS * D / 4; i += 256) {
        const int flat = i * 4;
        const int r = flat >> 7;
        const int c = flat & (D - 1);
        const int row = row0 + r;
        float4 hv = make_float4(0.f, 0.f, 0.f, 0.f);
        if (row < N) {
            const float4 xv = *(const float4*)(x   + (size_t)row * D + c);
            const float4 av = *(const float4*)(agg + (size_t)row * D + c);
            hv = make_float4(ep * xv.x + av.x, ep * xv.y + av.y,
                             ep * xv.z + av.z, ep * xv.w + av.w);
        }
        *(float4*)(hsh + r * HSTR + c) = hv;
    }
    __syncthreads();

    const int lane = threadIdx.x & 63;
    const int wrow = (threadIdx.x >> 6) * 16;  // wave's 16-row window
    const int m = lane & 15;
    const int q = lane >> 4;

    f32x4 acc[8];

    // ---- layer 1 ----
    #pragma unroll
    for (int ct = 0; ct < 8; ++ct) {
        const float b = b1[ct * 16 + m];
        acc[ct] = (f32x4){b, b, b, b};
    }
    #pragma unroll
    for (int ks = 0; ks < 4; ++ks) {
        const float* ap = hsh + (wrow + m) * HSTR + ks * 32 + q * 8;
        float av[8];
        *(float4*)(av)     = *(const float4*)ap;
        *(float4*)(av + 4) = *(const float4*)(ap + 4);
        bf16x8 a;
        #pragma unroll
        for (int j = 0; j < 8; ++j) a[j] = f2bf(av[j]);
        #pragma unroll
        for (int ct = 0; ct < 8; ++ct) {
            const bf16x8 b = *(const bf16x8*)(wb1t + (ct * 16 + m) * D + ks * 32 + q * 8);
            acc[ct] = __builtin_amdgcn_mfma_f32_16x16x32_bf16(a, b, acc[ct], 0, 0, 0);
        }
    }
    #pragma unroll
    for (int ct = 0; ct < 8; ++ct)
        #pragma unroll
        for (int r = 0; r < 4; ++r) {
            const float v = acc[ct][r];
            hsh[(wrow + q * 4 + r) * HSTR + ct * 16 + m] = v > 0.f ? v : 0.f;
        }

    // ---- layer 2 ----
    #pragma unroll
    for (int ct = 0; ct < 8; ++ct) {
        const float b = b2[ct * 16 + m];
        acc[ct] = (f32x4){b, b, b, b};
    }
    #pragma unroll
    for (int ks = 0; ks < 4; ++ks) {
        const float* ap = hsh + (wrow + m) * HSTR + ks * 32 + q * 8;
        float av[8];
        *(float4*)(av)     = *(const float4*)ap;
        *(float4*)(av + 4) = *(const float4*)(ap + 4);
        bf16x8 a;
        #pragma unroll
        for (int j = 0; j < 8; ++j) a[j] = f2bf(av[j]);
        #pragma unroll
        for (int ct = 0; ct < 8; ++ct) {
            const bf16x8 b = *(const bf16x8*)(wb2t + (ct * 16 + m) * D + ks * 32 + q * 8);
            acc[ct] = __builtin_amdgcn_mfma_f32_16x16x32_bf16(a, b, acc[ct], 0, 0, 0);
        }
    }
    #pragma unroll
    for (int r = 0; r < 4; ++r) {
        const int row = row0 + wrow + q * 4 + r;
        if (row < N) {
            #pragma unroll
            for (int ct = 0; ct < 8; ++ct)
                xres[(size_t)row * D + ct * 16 + m] = acc[ct][r];
        }
    }
}

// ---------------------------------------------------------------------------
// Stage 3: per-(graph,pocket) masked sums
// ---------------------------------------------------------------------------
#define PPARTS 32
__global__ __launch_bounds__(128) void pocket_sum_kernel(
    const float* __restrict__ xres, const float* __restrict__ pmask,
    const int* __restrict__ batch,
    float* __restrict__ psum, float* __restrict__ pcnt, int N)
{
    const int g = blockIdx.x / PPARTS;
    const int part = blockIdx.x % PPARTS;

    int lo, hi;
    {
        int l = 0, r = N;
        while (l < r) { int m = (l + r) >> 1; if (batch[m] < g) l = m + 1; else r = m; }
        lo = l;
        r = N;
        while (l < r) { int m = (l + r) >> 1; if (batch[m] < g + 1) l = m + 1; else r = m; }
        hi = l;
    }
    const int cnt = hi - lo;
    const int per = (cnt + PPARTS - 1) / PPARTS;
    const int s = lo + part * per;
    const int e = min(s + per, hi);

    const int d = threadIdx.x;
    float acc[K];
    #pragma unroll
    for (int k = 0; k < K; ++k) acc[k] = 0.0f;
    float c = 0.0f;

    for (int n = s; n < e; ++n) {
        const float xv = xres[(size_t)n * D + d];
        const float4 m0 = *(const float4*)(pmask + (size_t)n * K);
        const float4 m1 = *(const float4*)(pmask + (size_t)n * K + 4);
        acc[0] += m0.x * xv; acc[1] += m0.y * xv;
        acc[2] += m0.z * xv; acc[3] += m0.w * xv;
        acc[4] += m1.x * xv; acc[5] += m1.y * xv;
        acc[6] += m1.z * xv; acc[7] += m1.w * xv;
        if (d < K) c += pmask[(size_t)n * K + d];
    }
    #pragma unroll
    for (int k = 0; k < K; ++k)
        atomicAdd(&psum[(size_t)g * (K * D) + k * D + d], acc[k]);
    if (d < K) atomicAdd(&pcnt[g * K + d], c);
}

// ---------------------------------------------------------------------------
// Stage 4: pocket_emb = (psum / (pcnt + 1e-9)) @ Wv + bv
// ---------------------------------------------------------------------------
__global__ __launch_bounds__(128) void pocket_emb_kernel(
    const float* __restrict__ psum, const float* __restrict__ pcnt,
    const float* __restrict__ Wv, const float* __restrict__ bv,
    float* __restrict__ pemb)
{
    __shared__ float smean[K * D];
    __shared__ float scnt[K];
    const int g = blockIdx.x;
    const int d = threadIdx.x;
    if (d < K) scnt[d] = pcnt[g * K + d];
    __syncthreads();
    #pragma unroll
    for (int k = 0; k < K; ++k)
        smean[k * D + d] = psum[(size_t)g * (K * D) + k * D + d] / (scnt[k] + 1e-9f);
    __syncthreads();

    float acc[K];
    const float bvv = bv[d];
    #pragma unroll
    for (int k = 0; k < K; ++k) acc[k] = bvv;
    for (int j = 0; j < D; ++j) {
        const float w = Wv[j * D + d];
        #pragma unroll
        for (int k = 0; k < K; ++k) acc[k] += smean[k * D + j] * w;
    }
    #pragma unroll
    for (int k = 0; k < K; ++k)
        pemb[(size_t)g * (K * D) + k * D + d] = acc[k];
}

// ---------------------------------------------------------------------------
// Stage 5: feedback gather + LayerNorm + ReLU. One wave per node.
// ---------------------------------------------------------------------------
__global__ __launch_bounds__(256) void ln_kernel(
    const float* __restrict__ xres, const float* __restrict__ pmask,
    const int* __restrict__ batch, const float* __restrict__ pemb,
    const float* __restrict__ gamma, const float* __restrict__ beta,
    float* __restrict__ out, int N)
{
    const int wave = threadIdx.x >> 6;
    const int lane = threadIdx.x & 63;
    const int n = blockIdx.x * 4 + wave;
    if (n >= N) return;
    const int d = lane * 2;

    float2 v = *(const float2*)(xres + (size_t)n * D + d);
    const int g = batch[n];
    const float* pe = pemb + (size_t)g * (K * D);
    const float4 m0 = *(const float4*)(pmask + (size_t)n * K);
    const float4 m1 = *(const float4*)(pmask + (size_t)n * K + 4);
    const float mk[K] = {m0.x, m0.y, m0.z, m0.w, m1.x, m1.y, m1.z, m1.w};
    #pragma unroll
    for (int k = 0; k < K; ++k) {
        if (mk[k] != 0.0f) {   // wave-uniform branch
            const float2 p = *(const float2*)(pe + k * D + d);
            v.x += mk[k] * p.x;
            v.y += mk[k] * p.y;
        }
    }

    float s = v.x + v.y;
    #pragma unroll
    for (int off = 32; off; off >>= 1) s += __shfl_xor(s, off, 64);
    const float mu = s * (1.0f / 128.0f);
    const float d0 = v.x - mu, d1 = v.y - mu;
    float sq = d0 * d0 + d1 * d1;
    #pragma unroll
    for (int off = 32; off; off >>= 1) sq += __shfl_xor(sq, off, 64);
    const float var = sq * (1.0f / 128.0f);
    const float inv = rsqrtf(var + 1e-5f);

    const float2 gm = *(const float2*)(gamma + d);
    const float2 bt = *(const float2*)(beta + d);
    float y0 = d0 * inv * gm.x + bt.x;
    float y1 = d1 * inv * gm.y + bt.y;
    y0 = y0 > 0.0f ? y0 : 0.0f;
    y1 = y1 > 0.0f ? y1 : 0.0f;
    *(float2*)(out + (size_t)n * D + d) = make_float2(y0, y1);
}

// ---------------------------------------------------------------------------
extern "C" void kernel_launch(void* const* d_in, const int* in_sizes, int n_in,
                              void* d_out, int out_size, void* d_ws, size_t ws_size,
                              hipStream_t stream)
{
    const float* x     = (const float*)d_in[0];
    const int*   ei    = (const int*)  d_in[1];
    const float* ea    = (const float*)d_in[2];
    const float* pmask = (const float*)d_in[3];
    const int*   batch = (const int*)  d_in[4];
    const float* We    = (const float*)d_in[5];
    const float* be    = (const float*)d_in[6];
    const float* W1    = (const float*)d_in[7];
    const float* b1    = (const float*)d_in[8];
    const float* W2    = (const float*)d_in[9];
    const float* b2    = (const float*)d_in[10];
    const float* epsp  = (const float*)d_in[11];
    const float* gamma = (const float*)d_in[12];
    const float* beta  = (const float*)d_in[13];
    const float* Wv    = (const float*)d_in[14];
    const float* bv    = (const float*)d_in[15];
    float* out = (float*)d_out;

    const int N = in_sizes[0] / D;     // 50000
    const int E = in_sizes[1] / 2;     // 600000
    const int* src = ei;
    const int* dst = ei + E;

    // Workspace: [deg | agg | psum | pcnt] (single memset), xres (aliased
    // below), pemb, scan scratch, xb (bf16 x), wb1t/wb2t.
    int*   deg  = (int*)d_ws;                           // N
    float* agg  = (float*)(deg + N);                    // N*D
    float* psum = agg + (size_t)N * D;                  // B*K*D
    float* pcnt = psum + (size_t)BGRAPH * K * D;        // B*K
    float* xres = pcnt + (size_t)BGRAPH * K;            // N*D
    float* pemb = xres + (size_t)N * D;                 // B*K*D
    float* extra = pemb + (size_t)BGRAPH * K * D;       // scan scratch (128)
    __hip_bfloat16* xb = (__hip_bfloat16*)(extra + 128);// N*D bf16
    short* wb1t = (short*)(xb + (size_t)N * D);         // D*D bf16
    short* wb2t = wb1t + (size_t)D * D;                 // D*D bf16

    // Aliased inside xres region (cursor 0.2MB + md 4.8MB + eab 19.2MB
    // = 24.2MB < 25.6MB); all consumed before mlp writes xres.
    int*   cursor = (int*)xres;                         // N
    uint2* md  = (uint2*)(((uintptr_t)(cursor + N) + 15) & ~(uintptr_t)15); // E
    short* eab = (short*)(md + E);                      // E*16 bf16

    int*  bsum  = (int*)extra;                          // 64
    int*  boffs = bsum + 64;                            // 64

    const int nb = (N + 1023) / 1024;                   // scan blocks (49)
    const int nchunks = (E + CH - 1) / CH;              // 9375
    const int NX = N * D, NEA = E * 16;
    const int NBX = NX / 2048;                          // 3125 (exact)
    const int NBE = (NEA / 8 + 255) / 256;              // 4688
    const int NBW = (2 * D * D) / 256;                  // 128
    const int NBH = (E / 4 + 255) / 256;                // 586

    const size_t zero_bytes =
        ((size_t)N + (size_t)N * D + (size_t)BGRAPH * K * D + BGRAPH * K) * sizeof(float);
    hipMemsetAsync(d_ws, 0, zero_bytes, stream);

    prep_kernel<<<NBX + NBE + NBW + NBH, 256, 0, stream>>>(
        x, ea, W1, W2, dst, xb, eab, wb1t, wb2t, deg, NX, NEA, E, NBX, NBE, NBW);
    scan_partial_kernel<<<nb, 256, 0, stream>>>(deg, bsum, N);
    scan_top_kernel<<<1, 64, 0, stream>>>(bsum, boffs, nb);
    scan_final_kernel<<<nb, 256, 0, stream>>>(deg, boffs, cursor, N);
    scatter_kernel<<<(E + 255) / 256, 256, 0, stream>>>(src, dst, cursor, md, E);
    gine_reduce_kernel<<<(nchunks + 3) / 4, 256, 0, stream>>>(
        xb, md, eab, We, be, agg, E);

    mlp_mfma_kernel<<<(N + MROWS - 1) / MROWS, 256, 0, stream>>>(
        x, agg, epsp, wb1t, b1, wb2t, b2, xres, N);
    pocket_sum_kernel<<<BGRAPH * PPARTS, 128, 0, stream>>>(
        xres, pmask, batch, psum, pcnt, N);
    pocket_emb_kernel<<<BGRAPH, 128, 0, stream>>>(psum, pcnt, Wv, bv, pemb);
    ln_kernel<<<(N + 3) / 4, 256, 0, stream>>>(
        xres, pmask, batch, pemb, gamma, beta, out, N);
}